// Round 1
// baseline (13854.243 us; speedup 1.0000x reference)
//
#include <hip/hip_runtime.h>
#include <hip/hip_bf16.h>

// Sizes (fixed for this problem)
#define BATCH 2
#define LSEQ 512
#define DMODEL 1024
#define DINNER 2048
#define DSTATE 16
#define DTRANK 64
#define DCONV 4
#define EVENTD 10
#define TIMED 6
#define BT (BATCH*LSEQ)   // 1024

typedef unsigned int u32;
typedef unsigned short u16;

__device__ __forceinline__ float sigmoidf_(float x) { return 1.f/(1.f+__expf(-x)); }

// ---------------------------------------------------------------------------
// f32 -> bf16 (RNE) conversion for gru_whh
// ---------------------------------------------------------------------------
__global__ void f32_to_bf16(const float* __restrict__ src, u16* __restrict__ dst, int n) {
    for (int i = blockIdx.x*blockDim.x + threadIdx.x; i < n; i += gridDim.x*blockDim.x) {
        u32 u = __float_as_uint(src[i]);
        u32 r = (u + 0x7FFFu + ((u >> 16) & 1u)) >> 16;
        dst[i] = (u16)r;
    }
}

// ---------------------------------------------------------------------------
// Generic fp32 GEMM: C[M,N] = act(A[M,K(lda)] @ W[N,K]^T + bias_scale*bias[N])
// 64x64 tile, 256 threads, 4x4 per thread. ACT: 0=none, 1=softplus
// Assumes M % 64 == 0, K % 16 == 0. N arbitrary (bounds-checked).
// ---------------------------------------------------------------------------
template<int ACT>
__global__ void __launch_bounds__(256) gemm_nt(
    const float* __restrict__ A, int lda,
    const float* __restrict__ W,
    const float* __restrict__ bias, float bias_scale,
    float* __restrict__ C, int M, int N, int K) {
    // K-major LDS tiles (stride 72 floats = 288B, 16B-aligned rows) so the
    // compute loop reads float4 fragments (ds_read_b128).
    __shared__ __align__(16) float As[16*72];
    __shared__ __align__(16) float Ws[16*72];
    int tid = threadIdx.x;
    int tx = tid & 15, ty = tid >> 4;
    int m0 = blockIdx.y*64, n0 = blockIdx.x*64;
    float acc[4][4];
#pragma unroll
    for (int i = 0; i < 4; ++i)
#pragma unroll
        for (int j = 0; j < 4; ++j) acc[i][j] = 0.f;

    int kq = tid & 15;   // k within chunk
    int mq = tid >> 4;   // base row
    for (int k0 = 0; k0 < K; k0 += 16) {
#pragma unroll
        for (int r = 0; r < 4; ++r) {
            int m = mq + r*16;
            As[kq*72 + m] = A[(size_t)(m0+m)*lda + k0 + kq];
            int n = n0 + m;
            Ws[kq*72 + m] = (n < N) ? W[(size_t)n*K + k0 + kq] : 0.f;
        }
        __syncthreads();
#pragma unroll
        for (int kk = 0; kk < 16; ++kk) {
            float4 a4 = *(const float4*)&As[kk*72 + ty*4];
            float4 b4 = *(const float4*)&Ws[kk*72 + tx*4];
            float av[4] = {a4.x, a4.y, a4.z, a4.w};
            float bv[4] = {b4.x, b4.y, b4.z, b4.w};
#pragma unroll
            for (int i = 0; i < 4; ++i)
#pragma unroll
                for (int j = 0; j < 4; ++j) acc[i][j] += av[i]*bv[j];
        }
        __syncthreads();
    }
#pragma unroll
    for (int i = 0; i < 4; ++i) {
        int m = m0 + ty*4 + i;
#pragma unroll
        for (int j = 0; j < 4; ++j) {
            int n = n0 + tx*4 + j;
            if (n < N) {
                float v = acc[i][j];
                if (bias) v += bias_scale*bias[n];
                if (ACT == 1) v = (v > 20.f) ? v : log1pf(__expf(v));
                C[(size_t)m*N + n] = v;
            }
        }
    }
}

// ---------------------------------------------------------------------------
// Causal depthwise conv (width 4) + SiLU.  x_in = xz[:, :, :2048]
// ---------------------------------------------------------------------------
__global__ void conv_silu(const float* __restrict__ xz, const float* __restrict__ conv_w,
                          const float* __restrict__ conv_b, float* __restrict__ x_conv) {
    int idx = blockIdx.x*blockDim.x + threadIdx.x;       // BT*DINNER
    int d = idx & (DINNER-1);
    int bt = idx >> 11;
    int t = bt & (LSEQ-1); int b = bt >> 9;
    float acc = conv_b[d];
#pragma unroll
    for (int k = 0; k < DCONV; ++k) {
        int tt = t - (DCONV-1) + k;
        if (tt >= 0) acc += xz[((size_t)(b*LSEQ+tt))*(2*DINNER) + d] * conv_w[d*DCONV + k];
    }
    x_conv[idx] = acc * sigmoidf_(acc);
}

// ---------------------------------------------------------------------------
// Persistent GRU scan. 512 blocks x 256 threads, all co-resident.
// Block blk owns hidden units j in [blk*4, blk*4+4); wave u handles unit j0+u.
// gru_whh rows (bf16) for the block's 12 (gate,unit) pairs live in LDS.
// Grid barrier: hierarchical atomics + generation flag, device-scope fences.
// ---------------------------------------------------------------------------
__global__ void __launch_bounds__(256, 2) gru_kernel(
    const u16* __restrict__ whh_bf, const float* __restrict__ gi,
    const float* __restrict__ bhh, float* __restrict__ h_buf,
    float* __restrict__ h_gru, u32* __restrict__ bar) {
    __shared__ __align__(16) u16 wlds[12*DINNER];   // 48 KB
    int blk = blockIdx.x;
    int tid = threadIdx.x;
    int j0 = blk*4;
    {   // stage weights once (uint4 = 8 bf16 per load)
        uint4* dst = (uint4*)wlds;
        const uint4* src = (const uint4*)whh_bf;
        for (int i = tid; i < 12*256; i += 256) {
            int r = i >> 8, c = i & 255;
            int grow = (r >> 2)*DINNER + j0 + (r & 3);
            dst[i] = src[(size_t)grow*256 + c];
        }
    }
    __syncthreads();
    int wave = tid >> 6, lane = tid & 63;
    int u = wave;
    int j = j0 + u;
    const u32* wrow0 = (const u32*)(wlds + (0*4+u)*DINNER);
    const u32* wrow1 = (const u32*)(wlds + (1*4+u)*DINNER);
    const u32* wrow2 = (const u32*)(wlds + (2*4+u)*DINNER);
    float b_r = bhh[j], b_z = bhh[DINNER+j], b_n = bhh[2*DINNER+j];

    for (int t = 0; t < LSEQ; ++t) {
        int par = t & 1;
        const float* hin = h_buf + par*(2*DINNER);
        float ir0=0,iz0=0,inn0=0,ir1=0,iz1=0,inn1=0,hp0=0,hp1=0;
        if (lane == 0) {
            const float* g0 = gi + (size_t)t*(3*DINNER);
            const float* g1 = gi + (size_t)(LSEQ+t)*(3*DINNER);
            ir0 = g0[j]; iz0 = g0[DINNER+j]; inn0 = g0[2*DINNER+j];
            ir1 = g1[j]; iz1 = g1[DINNER+j]; inn1 = g1[2*DINNER+j];
            hp0 = hin[j]; hp1 = hin[DINNER+j];
        }
        float s00=0,s10=0,s20=0,s01=0,s11=0,s21=0;
        const float2* h0p = (const float2*)hin;
        const float2* h1p = (const float2*)(hin + DINNER);
#pragma unroll
        for (int i = 0; i < 16; ++i) {
            int ki = lane + (i << 6);
            float2 h0 = h0p[ki];
            float2 h1 = h1p[ki];
            u32 w0 = wrow0[ki], w1 = wrow1[ki], w2 = wrow2[ki];
            float w0e = __uint_as_float(w0 << 16), w0o = __uint_as_float(w0 & 0xFFFF0000u);
            float w1e = __uint_as_float(w1 << 16), w1o = __uint_as_float(w1 & 0xFFFF0000u);
            float w2e = __uint_as_float(w2 << 16), w2o = __uint_as_float(w2 & 0xFFFF0000u);
            s00 += w0e*h0.x + w0o*h0.y;
            s10 += w1e*h0.x + w1o*h0.y;
            s20 += w2e*h0.x + w2o*h0.y;
            s01 += w0e*h1.x + w0o*h1.y;
            s11 += w1e*h1.x + w1o*h1.y;
            s21 += w2e*h1.x + w2o*h1.y;
        }
#pragma unroll
        for (int off = 32; off; off >>= 1) {
            s00 += __shfl_xor(s00, off, 64); s10 += __shfl_xor(s10, off, 64);
            s20 += __shfl_xor(s20, off, 64); s01 += __shfl_xor(s01, off, 64);
            s11 += __shfl_xor(s11, off, 64); s21 += __shfl_xor(s21, off, 64);
        }
        if (lane == 0) {
            float* hout = h_buf + (1-par)*(2*DINNER);
            float r  = sigmoidf_(ir0 + s00 + b_r);
            float uu = sigmoidf_(iz0 + s10 + b_z);
            float nn = tanhf(inn0 + r*(s20 + b_n));
            float hn0 = (1.f-uu)*nn + uu*hp0;
            hout[j] = hn0;
            h_gru[(size_t)t*DINNER + j] = hn0;
            r  = sigmoidf_(ir1 + s01 + b_r);
            uu = sigmoidf_(iz1 + s11 + b_z);
            nn = tanhf(inn1 + r*(s21 + b_n));
            float hn1 = (1.f-uu)*nn + uu*hp1;
            hout[DINNER+j] = hn1;
            h_gru[(size_t)(LSEQ+t)*DINNER + j] = hn1;
        }
        // -------- grid barrier (all 512 blocks resident by construction) ----
        __syncthreads();   // drains this block's stores (vmcnt(0) before s_barrier)
        if (tid == 0) {
            __threadfence();   // device-scope release (cross-XCD visibility)
            u32 arrived = atomicAdd(&bar[(blk & 7) << 5], 1u) + 1u;
            if (arrived == (u32)((t+1)*64)) {
                u32 m = atomicAdd(&bar[8 << 5], 1u) + 1u;
                if (m == (u32)((t+1)*8)) {
                    __hip_atomic_store(&bar[9 << 5], (u32)(t+1),
                                       __ATOMIC_RELEASE, __HIP_MEMORY_SCOPE_AGENT);
                }
            }
            while (__hip_atomic_load(&bar[9 << 5], __ATOMIC_RELAXED,
                                     __HIP_MEMORY_SCOPE_AGENT) < (u32)(t+1)) {
                __builtin_amdgcn_s_sleep(2);
            }
            __threadfence();   // device-scope acquire (invalidate stale L1/L2)
        }
        __syncthreads();
    }
}

// ---------------------------------------------------------------------------
// scaling = clip(softplus(clip(h_gru . WT_w + WT_b, -10, 10)), 0.1, 10)
// stg = delta * scaling ; also emits scaling[:, -1] to d_out tail
// ---------------------------------------------------------------------------
__global__ void scaling_kernel(const float* __restrict__ h_gru, const float* __restrict__ WT_w,
                               const float* __restrict__ WT_b, const float* __restrict__ delta,
                               float* __restrict__ scaling, float* __restrict__ stg,
                               float* __restrict__ out_last) {
    __shared__ float red[4];
    int bt = blockIdx.x;
    int tid = threadIdx.x;
    const float* h = h_gru + (size_t)bt*DINNER;
    float p = 0.f;
    for (int k = tid; k < DINNER; k += 256) p += h[k]*WT_w[k];
#pragma unroll
    for (int off = 32; off; off >>= 1) p += __shfl_down(p, off, 64);
    if ((tid & 63) == 0) red[tid >> 6] = p;
    __syncthreads();
    if (tid == 0) {
        float v = red[0]+red[1]+red[2]+red[3] + WT_b[0];
        v = fminf(fmaxf(v, -10.f), 10.f);
        float sp = log1pf(__expf(v));
        sp = fminf(fmaxf(sp, 0.1f), 10.f);
        scaling[bt] = sp;
        stg[bt] = delta[bt]*sp;
        if ((bt & (LSEQ-1)) == LSEQ-1) out_last[bt >> 9] = sp;
    }
}

__global__ void intervals_kernel(const float* __restrict__ stg, float* __restrict__ intervals) {
    int idx = blockIdx.x*256 + threadIdx.x;
    if (idx < BT) {
        float v = stg[idx];
        if (idx & (LSEQ-1)) v -= stg[idx-1];
        intervals[idx] = v;
    }
}

// B_dual = sigmoid([content | stg*Wtau]) * B0
__global__ void bdual_kernel(const float* __restrict__ content, const float* __restrict__ stg,
                             const float* __restrict__ Wtau_w, const float* __restrict__ B0,
                             float* __restrict__ B_dual) {
    int idx = blockIdx.x*256 + threadIdx.x;      // BT*16
    int n = idx & 15, bt = idx >> 4;
    float v = (n < EVENTD) ? content[bt*EVENTD + n] : stg[bt]*Wtau_w[n - EVENTD];
    B_dual[idx] = B0[n]*sigmoidf_(v);
}

// ---------------------------------------------------------------------------
// Fused selective scan + y epilogue. One thread per (b,d); 16 states in regs.
// y_full = (sum_n h_n*C_n + x_conv*D) * silu(z)
// ---------------------------------------------------------------------------
__global__ void scan_kernel(const float* __restrict__ base_dt, const float* __restrict__ intervals,
                            const float* __restrict__ B_dual, const float* __restrict__ x_dbl,
                            const float* __restrict__ x_conv, const float* __restrict__ xz,
                            const float* __restrict__ A_log, const float* __restrict__ D_param,
                            float* __restrict__ y_full) {
    int idx = blockIdx.x*256 + threadIdx.x;      // 2*2048
    int d = idx & (DINNER-1);
    int b = idx >> 11;
    float Arow[DSTATE];
#pragma unroll
    for (int n = 0; n < DSTATE; ++n) Arow[n] = -__expf(A_log[d*DSTATE + n]);
    float Dd = D_param[d];
    float h[DSTATE];
#pragma unroll
    for (int n = 0; n < DSTATE; ++n) h[n] = 0.f;
    for (int t = 0; t < LSEQ; ++t) {
        size_t row = (size_t)b*LSEQ + t;
        float dt = intervals[row]*base_dt[row*DINNER + d];
        dt = fminf(fmaxf(dt, 1e-6f), 10.f);
        float xc = x_conv[row*DINNER + d];
        const float* Bd = B_dual + row*DSTATE;
        const float* Cc = x_dbl + row*96 + DTRANK + DSTATE;   // C = cols 80..95
        float y = 0.f;
#pragma unroll
        for (int n = 0; n < DSTATE; ++n) {
            float e = dt*Arow[n];
            e = fminf(fmaxf(e, -20.f), 20.f);
            float da = __expf(e);
            h[n] = da*h[n] + (dt*Bd[n])*xc;
            y += h[n]*Cc[n];
        }
        float z = xz[row*(2*DINNER) + DINNER + d];
        y_full[row*DINNER + d] = (y + xc*Dd) * (z*sigmoidf_(z));
    }
}

// ---------------------------------------------------------------------------
extern "C" void kernel_launch(void* const* d_in, const int* in_sizes, int n_in,
                              void* d_out, int out_size, void* d_ws, size_t ws_size,
                              hipStream_t stream) {
    const float* x         = (const float*)d_in[0];
    const float* delta     = (const float*)d_in[1];
    const float* in_proj_w = (const float*)d_in[2];
    const float* conv_w    = (const float*)d_in[3];
    const float* conv_b    = (const float*)d_in[4];
    const float* gru_wih   = (const float*)d_in[5];
    const float* gru_whh   = (const float*)d_in[6];
    const float* gru_bih   = (const float*)d_in[7];
    const float* gru_bhh   = (const float*)d_in[8];
    const float* WT_w      = (const float*)d_in[9];
    const float* WT_b      = (const float*)d_in[10];
    const float* Wc_w      = (const float*)d_in[11];
    const float* Wtau_w    = (const float*)d_in[12];
    const float* B0        = (const float*)d_in[13];
    const float* xproj_w   = (const float*)d_in[14];
    const float* dtproj_w  = (const float*)d_in[15];
    const float* dtproj_b  = (const float*)d_in[16];
    const float* A_log     = (const float*)d_in[17];
    const float* D_param   = (const float*)d_in[18];
    const float* outproj_w = (const float*)d_in[19];
    float* out = (float*)d_out;

    // Workspace layout (float units); ~93 MB total
    float* ws = (float*)d_ws;
    size_t off = 0;
    float* xz      = ws + off; off += (size_t)BT*2*DINNER;          // 4,194,304
    float* x_conv  = ws + off; off += (size_t)BT*DINNER;            // 2,097,152
    float* gi      = ws + off; off += (size_t)BT*3*DINNER;          // 6,291,456 (reused as y_full)
    u16*   whh_bf  = (u16*)(ws + off); off += (size_t)3*DINNER*DINNER/2; // 25.2 MB
    float* h_gru   = ws + off; off += (size_t)BT*DINNER;
    float* base_dt = ws + off; off += (size_t)BT*DINNER;
    float* x_dbl   = ws + off; off += (size_t)BT*96;
    float* content = ws + off; off += (size_t)BT*16;
    float* B_dual  = ws + off; off += (size_t)BT*16;
    float* scaling = ws + off; off += BT;
    float* stg     = ws + off; off += BT;
    float* intervals = ws + off; off += BT;
    float* h_buf   = ws + off; off += 2*2*DINNER;                   // [parity][batch][d]
    u32*   bar     = (u32*)(ws + off); off += 512;
    float* y_full  = gi;   // gi dead after GRU

    // zero h state + barrier counters (ws is re-poisoned 0xAA before every call)
    hipMemsetAsync(h_buf, 0, (2*2*DINNER)*sizeof(float) + 512*sizeof(u32), stream);

    f32_to_bf16<<<4096, 256, 0, stream>>>(gru_whh, whh_bf, 3*DINNER*DINNER);

    // xz = x @ in_proj_w.T            (1024 x 4096, K=1024)
    gemm_nt<0><<<dim3(64,16), 256, 0, stream>>>(x, DMODEL, in_proj_w, nullptr, 0.f,
                                                xz, BT, 2*DINNER, DMODEL);
    conv_silu<<<(BT*DINNER)/256, 256, 0, stream>>>(xz, conv_w, conv_b, x_conv);

    // gi = x_conv @ gru_wih.T + bih   (1024 x 6144, K=2048)
    gemm_nt<0><<<dim3(96,16), 256, 0, stream>>>(x_conv, DINNER, gru_wih, gru_bih, 1.f,
                                                gi, BT, 3*DINNER, DINNER);

    gru_kernel<<<512, 256, 0, stream>>>(whh_bf, gi, gru_bhh, h_buf, h_gru, bar);

    scaling_kernel<<<BT, 256, 0, stream>>>(h_gru, WT_w, WT_b, delta, scaling, stg,
                                           out + (size_t)BT*DMODEL);
    intervals_kernel<<<4, 256, 0, stream>>>(stg, intervals);

    // x_dbl = x_conv @ xproj_w.T      (1024 x 96, K=2048)
    gemm_nt<0><<<dim3(2,16), 256, 0, stream>>>(x_conv, DINNER, xproj_w, nullptr, 0.f,
                                               x_dbl, BT, 96, DINNER);
    // base_dt = softplus(dt_low @ dtproj_w.T + 2*dtproj_b)   (1024 x 2048, K=64)
    gemm_nt<1><<<dim3(32,16), 256, 0, stream>>>(x_dbl, 96, dtproj_w, dtproj_b, 2.f,
                                                base_dt, BT, DINNER, DTRANK);
    // content = x_conv @ Wc_w.T       (1024 x 10, K=2048)
    gemm_nt<0><<<dim3(1,16), 256, 0, stream>>>(x_conv, DINNER, Wc_w, nullptr, 0.f,
                                               content, BT, EVENTD, DINNER);
    bdual_kernel<<<(BT*16)/256, 256, 0, stream>>>(content, stg, Wtau_w, B0, B_dual);

    scan_kernel<<<(BATCH*DINNER)/256, 256, 0, stream>>>(base_dt, intervals, B_dual, x_dbl,
                                                        x_conv, xz, A_log, D_param, y_full);

    // out = y_full @ outproj_w.T      (1024 x 1024, K=2048)
    gemm_nt<0><<<dim3(16,16), 256, 0, stream>>>(y_full, DINNER, outproj_w, nullptr, 0.f,
                                                out, BT, DMODEL, DINNER);
}

// Round 2
// 6700.179 us; speedup vs baseline: 2.0677x; 2.0677x over previous
//
#include <hip/hip_runtime.h>
#include <hip/hip_bf16.h>

// Sizes (fixed for this problem)
#define BATCH 2
#define LSEQ 512
#define DMODEL 1024
#define DINNER 2048
#define DSTATE 16
#define DTRANK 64
#define DCONV 4
#define EVENTD 10
#define TIMED 6
#define BT (BATCH*LSEQ)   // 1024

typedef unsigned int u32;
typedef unsigned short u16;
typedef unsigned long long u64;

__device__ __forceinline__ float sigmoidf_(float x) { return 1.f/(1.f+__expf(-x)); }

// ---------------------------------------------------------------------------
// f32 -> bf16 (RNE) conversion for gru_whh
// ---------------------------------------------------------------------------
__global__ void f32_to_bf16(const float* __restrict__ src, u16* __restrict__ dst, int n) {
    for (int i = blockIdx.x*blockDim.x + threadIdx.x; i < n; i += gridDim.x*blockDim.x) {
        u32 u = __float_as_uint(src[i]);
        u32 r = (u + 0x7FFFu + ((u >> 16) & 1u)) >> 16;
        dst[i] = (u16)r;
    }
}

// ---------------------------------------------------------------------------
// Generic fp32 GEMM: C[M,N] = act(A[M,K(lda)] @ W[N,K]^T + bias_scale*bias[N])
// 64x64 tile, 256 threads, 4x4 per thread. ACT: 0=none, 1=softplus
// ---------------------------------------------------------------------------
template<int ACT>
__global__ void __launch_bounds__(256) gemm_nt(
    const float* __restrict__ A, int lda,
    const float* __restrict__ W,
    const float* __restrict__ bias, float bias_scale,
    float* __restrict__ C, int M, int N, int K) {
    __shared__ __align__(16) float As[16*72];
    __shared__ __align__(16) float Ws[16*72];
    int tid = threadIdx.x;
    int tx = tid & 15, ty = tid >> 4;
    int m0 = blockIdx.y*64, n0 = blockIdx.x*64;
    float acc[4][4];
#pragma unroll
    for (int i = 0; i < 4; ++i)
#pragma unroll
        for (int j = 0; j < 4; ++j) acc[i][j] = 0.f;

    int kq = tid & 15;
    int mq = tid >> 4;
    for (int k0 = 0; k0 < K; k0 += 16) {
#pragma unroll
        for (int r = 0; r < 4; ++r) {
            int m = mq + r*16;
            As[kq*72 + m] = A[(size_t)(m0+m)*lda + k0 + kq];
            int n = n0 + m;
            Ws[kq*72 + m] = (n < N) ? W[(size_t)n*K + k0 + kq] : 0.f;
        }
        __syncthreads();
#pragma unroll
        for (int kk = 0; kk < 16; ++kk) {
            float4 a4 = *(const float4*)&As[kk*72 + ty*4];
            float4 b4 = *(const float4*)&Ws[kk*72 + tx*4];
            float av[4] = {a4.x, a4.y, a4.z, a4.w};
            float bv[4] = {b4.x, b4.y, b4.z, b4.w};
#pragma unroll
            for (int i = 0; i < 4; ++i)
#pragma unroll
                for (int j = 0; j < 4; ++j) acc[i][j] += av[i]*bv[j];
        }
        __syncthreads();
    }
#pragma unroll
    for (int i = 0; i < 4; ++i) {
        int m = m0 + ty*4 + i;
#pragma unroll
        for (int j = 0; j < 4; ++j) {
            int n = n0 + tx*4 + j;
            if (n < N) {
                float v = acc[i][j];
                if (bias) v += bias_scale*bias[n];
                if (ACT == 1) v = (v > 20.f) ? v : log1pf(__expf(v));
                C[(size_t)m*N + n] = v;
            }
        }
    }
}

// ---------------------------------------------------------------------------
// Causal depthwise conv (width 4) + SiLU.
// ---------------------------------------------------------------------------
__global__ void conv_silu(const float* __restrict__ xz, const float* __restrict__ conv_w,
                          const float* __restrict__ conv_b, float* __restrict__ x_conv) {
    int idx = blockIdx.x*blockDim.x + threadIdx.x;
    int d = idx & (DINNER-1);
    int bt = idx >> 11;
    int t = bt & (LSEQ-1); int b = bt >> 9;
    float acc = conv_b[d];
#pragma unroll
    for (int k = 0; k < DCONV; ++k) {
        int tt = t - (DCONV-1) + k;
        if (tt >= 0) acc += xz[((size_t)(b*LSEQ+tt))*(2*DINNER) + d] * conv_w[d*DCONV + k];
    }
    x_conv[idx] = acc * sigmoidf_(acc);
}

// ---------------------------------------------------------------------------
// Persistent GRU scan v2 — fenceless tagged dataflow.
// 128 blocks x 512 threads (8 waves). Block owns 16 units; wave owns 2 units
// (x3 gates x2 batches = 12 dot products of length 2048). Weights: 96 VGPRs
// of packed bf16 per lane, loaded once. Hidden-state exchange: each value is
// published as a 64-bit (tag<<32 | f32bits) relaxed AGENT-scope atomic — the
// tag makes fences unnecessary (data rides inside the atomic word).
// Double buffer by parity; WAR-free by induction: S_{t+2} can only be written
// after every block has staged S_t into its LDS.
// ---------------------------------------------------------------------------
#define GRU_NBLK 128
#define GRU_THREADS 512

__global__ void __launch_bounds__(GRU_THREADS, 2) gru_kernel(
    const u32* __restrict__ whh_u32, const float* __restrict__ gi,
    const float* __restrict__ bhh, u64* __restrict__ hT,
    float* __restrict__ h_gru) {
    __shared__ __align__(16) float h_lds[2*DINNER];   // 16 KB: [b][j]
    int blk = blockIdx.x;
    int tid = threadIdx.x;
    int w = tid >> 6, lane = tid & 63;
    int j0 = blk*16;

    // ---- preload weights: 6 rows (g in 0..2, u in 0..1), 16 u32 each ----
    u32 wr[6][16];
#pragma unroll
    for (int r6 = 0; r6 < 6; ++r6) {
        int g = r6 >> 1, u = r6 & 1;
        int j = j0 + 2*w + u;
        const u32* row = whh_u32 + ((size_t)(g*DINNER + j))*(DINNER/2);
#pragma unroll
        for (int i = 0; i < 16; ++i) wr[r6][i] = row[lane + 64*i];
    }
    // ---- per-lane combo (lanes 0..3 finalize a (unit,batch) pair) ----
    float b_r = 0.f, b_z = 0.f, b_n = 0.f;
    int jme = 0, bme = 0;
    if (lane < 4) {
        int u = lane & 1; bme = lane >> 1;
        jme = j0 + 2*w + u;
        b_r = bhh[jme]; b_z = bhh[DINNER+jme]; b_n = bhh[2*DINNER+jme];
    }

    for (int t = 0; t < LSEQ; ++t) {
        int par = t & 1;
        // prefetch gi for this step (independent of the spin)
        float ir = 0.f, iz = 0.f, inn = 0.f;
        if (lane < 4) {
            const float* g0 = gi + ((size_t)(bme*LSEQ + t))*(3*DINNER);
            ir = g0[jme]; iz = g0[DINNER+jme]; inn = g0[2*DINNER+jme];
        }
        // ---- stage S_t into LDS (spin on tags) ----
        {
            const u64* src = hT + (size_t)par*(2*DINNER);
            u64 v[8]; int idxs[8];
#pragma unroll
            for (int r = 0; r < 8; ++r) {
                idxs[r] = tid + GRU_THREADS*r;
                v[r] = __hip_atomic_load(&src[idxs[r]], __ATOMIC_RELAXED,
                                         __HIP_MEMORY_SCOPE_AGENT);
            }
#pragma unroll
            for (int r = 0; r < 8; ++r) {
                while ((u32)(v[r] >> 32) < (u32)t) {
                    __builtin_amdgcn_s_sleep(1);
                    v[r] = __hip_atomic_load(&src[idxs[r]], __ATOMIC_RELAXED,
                                             __HIP_MEMORY_SCOPE_AGENT);
                }
                h_lds[idxs[r]] = __uint_as_float((u32)v[r]);
            }
        }
        __syncthreads();
        // ---- 12 dot products per wave from LDS x register weights ----
        float s[12];
#pragma unroll
        for (int q = 0; q < 12; ++q) s[q] = 0.f;
        const float2* hl0 = (const float2*)&h_lds[0];
        const float2* hl1 = (const float2*)&h_lds[DINNER];
#pragma unroll
        for (int i = 0; i < 16; ++i) {
            int k2 = lane + 64*i;
            float2 h0 = hl0[k2];
            float2 h1 = hl1[k2];
#pragma unroll
            for (int r6 = 0; r6 < 6; ++r6) {
                u32 wv = wr[r6][i];
                float we = __uint_as_float(wv << 16);
                float wo = __uint_as_float(wv & 0xFFFF0000u);
                s[r6*2+0] += we*h0.x + wo*h0.y;
                s[r6*2+1] += we*h1.x + wo*h1.y;
            }
        }
#pragma unroll
        for (int off = 32; off; off >>= 1)
#pragma unroll
            for (int q = 0; q < 12; ++q) s[q] += __shfl_xor(s[q], off, 64);

        if (lane < 4) {
            int u = lane & 1;
            float sr = s[(0*2+u)*2 + bme];
            float sz = s[(1*2+u)*2 + bme];
            float sn = s[(2*2+u)*2 + bme];
            float hp = h_lds[bme*DINNER + jme];
            float r  = sigmoidf_(ir + sr + b_r);
            float uu = sigmoidf_(iz + sz + b_z);
            float nn = tanhf(inn + r*(sn + b_n));
            float hn = (1.f-uu)*nn + uu*hp;
            h_gru[((size_t)(bme*LSEQ + t))*DINNER + jme] = hn;
            u64 pk = ((u64)(u32)(t+1) << 32) | (u64)__float_as_uint(hn);
            __hip_atomic_store(&hT[(size_t)(1-par)*(2*DINNER) + bme*DINNER + jme],
                               pk, __ATOMIC_RELAXED, __HIP_MEMORY_SCOPE_AGENT);
        }
        __syncthreads();   // protect h_lds before next step's staging
    }
}

// ---------------------------------------------------------------------------
// scaling = clip(softplus(clip(h_gru . WT_w + WT_b, -10, 10)), 0.1, 10)
// ---------------------------------------------------------------------------
__global__ void scaling_kernel(const float* __restrict__ h_gru, const float* __restrict__ WT_w,
                               const float* __restrict__ WT_b, const float* __restrict__ delta,
                               float* __restrict__ scaling, float* __restrict__ stg,
                               float* __restrict__ out_last) {
    __shared__ float red[4];
    int bt = blockIdx.x;
    int tid = threadIdx.x;
    const float* h = h_gru + (size_t)bt*DINNER;
    float p = 0.f;
    for (int k = tid; k < DINNER; k += 256) p += h[k]*WT_w[k];
#pragma unroll
    for (int off = 32; off; off >>= 1) p += __shfl_down(p, off, 64);
    if ((tid & 63) == 0) red[tid >> 6] = p;
    __syncthreads();
    if (tid == 0) {
        float v = red[0]+red[1]+red[2]+red[3] + WT_b[0];
        v = fminf(fmaxf(v, -10.f), 10.f);
        float sp = log1pf(__expf(v));
        sp = fminf(fmaxf(sp, 0.1f), 10.f);
        scaling[bt] = sp;
        stg[bt] = delta[bt]*sp;
        if ((bt & (LSEQ-1)) == LSEQ-1) out_last[bt >> 9] = sp;
    }
}

__global__ void intervals_kernel(const float* __restrict__ stg, float* __restrict__ intervals) {
    int idx = blockIdx.x*256 + threadIdx.x;
    if (idx < BT) {
        float v = stg[idx];
        if (idx & (LSEQ-1)) v -= stg[idx-1];
        intervals[idx] = v;
    }
}

__global__ void bdual_kernel(const float* __restrict__ content, const float* __restrict__ stg,
                             const float* __restrict__ Wtau_w, const float* __restrict__ B0,
                             float* __restrict__ B_dual) {
    int idx = blockIdx.x*256 + threadIdx.x;
    int n = idx & 15, bt = idx >> 4;
    float v = (n < EVENTD) ? content[bt*EVENTD + n] : stg[bt]*Wtau_w[n - EVENTD];
    B_dual[idx] = B0[n]*sigmoidf_(v);
}

// ---------------------------------------------------------------------------
// Fused selective scan + y epilogue. One thread per (b,d).
// ---------------------------------------------------------------------------
__global__ void scan_kernel(const float* __restrict__ base_dt, const float* __restrict__ intervals,
                            const float* __restrict__ B_dual, const float* __restrict__ x_dbl,
                            const float* __restrict__ x_conv, const float* __restrict__ xz,
                            const float* __restrict__ A_log, const float* __restrict__ D_param,
                            float* __restrict__ y_full) {
    int idx = blockIdx.x*256 + threadIdx.x;
    int d = idx & (DINNER-1);
    int b = idx >> 11;
    float Arow[DSTATE];
#pragma unroll
    for (int n = 0; n < DSTATE; ++n) Arow[n] = -__expf(A_log[d*DSTATE + n]);
    float Dd = D_param[d];
    float h[DSTATE];
#pragma unroll
    for (int n = 0; n < DSTATE; ++n) h[n] = 0.f;
    for (int t = 0; t < LSEQ; ++t) {
        size_t row = (size_t)b*LSEQ + t;
        float dt = intervals[row]*base_dt[row*DINNER + d];
        dt = fminf(fmaxf(dt, 1e-6f), 10.f);
        float xc = x_conv[row*DINNER + d];
        const float* Bd = B_dual + row*DSTATE;
        const float* Cc = x_dbl + row*96 + DTRANK + DSTATE;
        float y = 0.f;
#pragma unroll
        for (int n = 0; n < DSTATE; ++n) {
            float e = dt*Arow[n];
            e = fminf(fmaxf(e, -20.f), 20.f);
            float da = __expf(e);
            h[n] = da*h[n] + (dt*Bd[n])*xc;
            y += h[n]*Cc[n];
        }
        float z = xz[row*(2*DINNER) + DINNER + d];
        y_full[row*DINNER + d] = (y + xc*Dd) * (z*sigmoidf_(z));
    }
}

// ---------------------------------------------------------------------------
extern "C" void kernel_launch(void* const* d_in, const int* in_sizes, int n_in,
                              void* d_out, int out_size, void* d_ws, size_t ws_size,
                              hipStream_t stream) {
    const float* x         = (const float*)d_in[0];
    const float* delta     = (const float*)d_in[1];
    const float* in_proj_w = (const float*)d_in[2];
    const float* conv_w    = (const float*)d_in[3];
    const float* conv_b    = (const float*)d_in[4];
    const float* gru_wih   = (const float*)d_in[5];
    const float* gru_whh   = (const float*)d_in[6];
    const float* gru_bih   = (const float*)d_in[7];
    const float* gru_bhh   = (const float*)d_in[8];
    const float* WT_w      = (const float*)d_in[9];
    const float* WT_b      = (const float*)d_in[10];
    const float* Wc_w      = (const float*)d_in[11];
    const float* Wtau_w    = (const float*)d_in[12];
    const float* B0        = (const float*)d_in[13];
    const float* xproj_w   = (const float*)d_in[14];
    const float* dtproj_w  = (const float*)d_in[15];
    const float* dtproj_b  = (const float*)d_in[16];
    const float* A_log     = (const float*)d_in[17];
    const float* D_param   = (const float*)d_in[18];
    const float* outproj_w = (const float*)d_in[19];
    float* out = (float*)d_out;

    float* ws = (float*)d_ws;
    size_t off = 0;
    float* xz      = ws + off; off += (size_t)BT*2*DINNER;
    float* x_conv  = ws + off; off += (size_t)BT*DINNER;
    float* gi      = ws + off; off += (size_t)BT*3*DINNER;     // reused as y_full
    u16*   whh_bf  = (u16*)(ws + off); off += (size_t)3*DINNER*DINNER/2;
    float* h_gru   = ws + off; off += (size_t)BT*DINNER;
    float* base_dt = ws + off; off += (size_t)BT*DINNER;
    float* x_dbl   = ws + off; off += (size_t)BT*96;
    float* content = ws + off; off += (size_t)BT*16;
    float* B_dual  = ws + off; off += (size_t)BT*16;
    float* scaling = ws + off; off += BT;
    float* stg     = ws + off; off += BT;
    float* intervals = ws + off; off += BT;
    u64*   hT      = (u64*)(ws + off); off += 2*(2*2*DINNER);  // tagged h, 2 parities
    float* y_full  = gi;

    // init tagged-h buffers: tag=0, value=0 (both parities)
    hipMemsetAsync(hT, 0, (size_t)2*2*DINNER*sizeof(u64), stream);

    f32_to_bf16<<<4096, 256, 0, stream>>>(gru_whh, whh_bf, 3*DINNER*DINNER);

    // xz = x @ in_proj_w.T            (1024 x 4096, K=1024)
    gemm_nt<0><<<dim3(64,16), 256, 0, stream>>>(x, DMODEL, in_proj_w, nullptr, 0.f,
                                                xz, BT, 2*DINNER, DMODEL);
    conv_silu<<<(BT*DINNER)/256, 256, 0, stream>>>(xz, conv_w, conv_b, x_conv);

    // gi = x_conv @ gru_wih.T + bih   (1024 x 6144, K=2048)
    gemm_nt<0><<<dim3(96,16), 256, 0, stream>>>(x_conv, DINNER, gru_wih, gru_bih, 1.f,
                                                gi, BT, 3*DINNER, DINNER);

    gru_kernel<<<GRU_NBLK, GRU_THREADS, 0, stream>>>((const u32*)whh_bf, gi, gru_bhh,
                                                     hT, h_gru);

    scaling_kernel<<<BT, 256, 0, stream>>>(h_gru, WT_w, WT_b, delta, scaling, stg,
                                           out + (size_t)BT*DMODEL);
    intervals_kernel<<<4, 256, 0, stream>>>(stg, intervals);

    // x_dbl = x_conv @ xproj_w.T      (1024 x 96, K=2048)
    gemm_nt<0><<<dim3(2,16), 256, 0, stream>>>(x_conv, DINNER, xproj_w, nullptr, 0.f,
                                               x_dbl, BT, 96, DINNER);
    // base_dt = softplus(dt_low @ dtproj_w.T + 2*dtproj_b)
    gemm_nt<1><<<dim3(32,16), 256, 0, stream>>>(x_dbl, 96, dtproj_w, dtproj_b, 2.f,
                                                base_dt, BT, DINNER, DTRANK);
    // content = x_conv @ Wc_w.T       (1024 x 10, K=2048)
    gemm_nt<0><<<dim3(1,16), 256, 0, stream>>>(x_conv, DINNER, Wc_w, nullptr, 0.f,
                                               content, BT, EVENTD, DINNER);
    bdual_kernel<<<(BT*16)/256, 256, 0, stream>>>(content, stg, Wtau_w, B0, B_dual);

    scan_kernel<<<(BATCH*DINNER)/256, 256, 0, stream>>>(base_dt, intervals, B_dual, x_dbl,
                                                        x_conv, xz, A_log, D_param, y_full);

    // out = y_full @ outproj_w.T      (1024 x 1024, K=2048)
    gemm_nt<0><<<dim3(16,16), 256, 0, stream>>>(y_full, DINNER, outproj_w, nullptr, 0.f,
                                                out, BT, DMODEL, DINNER);
}

// Round 3
// 5747.757 us; speedup vs baseline: 2.4104x; 1.1657x over previous
//
#include <hip/hip_runtime.h>
#include <hip/hip_bf16.h>

// Sizes (fixed for this problem)
#define BATCH 2
#define LSEQ 512
#define DMODEL 1024
#define DINNER 2048
#define DSTATE 16
#define DTRANK 64
#define DCONV 4
#define EVENTD 10
#define TIMED 6
#define BT (BATCH*LSEQ)   // 1024

typedef unsigned int u32;
typedef unsigned short u16;
typedef unsigned long long u64;

__device__ __forceinline__ float sigmoidf_(float x) { return 1.f/(1.f+__expf(-x)); }

// ---------------------------------------------------------------------------
// f32 -> bf16 (RNE) conversion for gru_whh
// ---------------------------------------------------------------------------
__global__ void f32_to_bf16(const float* __restrict__ src, u16* __restrict__ dst, int n) {
    for (int i = blockIdx.x*blockDim.x + threadIdx.x; i < n; i += gridDim.x*blockDim.x) {
        u32 u = __float_as_uint(src[i]);
        u32 r = (u + 0x7FFFu + ((u >> 16) & 1u)) >> 16;
        dst[i] = (u16)r;
    }
}

// ---------------------------------------------------------------------------
// Generic fp32 GEMM: C[M,N] = act(A[M,K(lda)] @ W[N,K]^T + bias_scale*bias[N])
// 64x64 tile, 256 threads, 4x4 per thread. ACT: 0=none, 1=softplus
// ---------------------------------------------------------------------------
template<int ACT>
__global__ void __launch_bounds__(256) gemm_nt(
    const float* __restrict__ A, int lda,
    const float* __restrict__ W,
    const float* __restrict__ bias, float bias_scale,
    float* __restrict__ C, int M, int N, int K) {
    __shared__ __align__(16) float As[16*72];
    __shared__ __align__(16) float Ws[16*72];
    int tid = threadIdx.x;
    int tx = tid & 15, ty = tid >> 4;
    int m0 = blockIdx.y*64, n0 = blockIdx.x*64;
    float acc[4][4];
#pragma unroll
    for (int i = 0; i < 4; ++i)
#pragma unroll
        for (int j = 0; j < 4; ++j) acc[i][j] = 0.f;

    int kq = tid & 15;
    int mq = tid >> 4;
    for (int k0 = 0; k0 < K; k0 += 16) {
#pragma unroll
        for (int r = 0; r < 4; ++r) {
            int m = mq + r*16;
            As[kq*72 + m] = A[(size_t)(m0+m)*lda + k0 + kq];
            int n = n0 + m;
            Ws[kq*72 + m] = (n < N) ? W[(size_t)n*K + k0 + kq] : 0.f;
        }
        __syncthreads();
#pragma unroll
        for (int kk = 0; kk < 16; ++kk) {
            float4 a4 = *(const float4*)&As[kk*72 + ty*4];
            float4 b4 = *(const float4*)&Ws[kk*72 + tx*4];
            float av[4] = {a4.x, a4.y, a4.z, a4.w};
            float bv[4] = {b4.x, b4.y, b4.z, b4.w};
#pragma unroll
            for (int i = 0; i < 4; ++i)
#pragma unroll
                for (int j = 0; j < 4; ++j) acc[i][j] += av[i]*bv[j];
        }
        __syncthreads();
    }
#pragma unroll
    for (int i = 0; i < 4; ++i) {
        int m = m0 + ty*4 + i;
#pragma unroll
        for (int j = 0; j < 4; ++j) {
            int n = n0 + tx*4 + j;
            if (n < N) {
                float v = acc[i][j];
                if (bias) v += bias_scale*bias[n];
                if (ACT == 1) v = (v > 20.f) ? v : log1pf(__expf(v));
                C[(size_t)m*N + n] = v;
            }
        }
    }
}

// ---------------------------------------------------------------------------
// Causal depthwise conv (width 4) + SiLU.
// ---------------------------------------------------------------------------
__global__ void conv_silu(const float* __restrict__ xz, const float* __restrict__ conv_w,
                          const float* __restrict__ conv_b, float* __restrict__ x_conv) {
    int idx = blockIdx.x*blockDim.x + threadIdx.x;
    int d = idx & (DINNER-1);
    int bt = idx >> 11;
    int t = bt & (LSEQ-1); int b = bt >> 9;
    float acc = conv_b[d];
#pragma unroll
    for (int k = 0; k < DCONV; ++k) {
        int tt = t - (DCONV-1) + k;
        if (tt >= 0) acc += xz[((size_t)(b*LSEQ+tt))*(2*DINNER) + d] * conv_w[d*DCONV + k];
    }
    x_conv[idx] = acc * sigmoidf_(acc);
}

// ---------------------------------------------------------------------------
// Persistent GRU scan v3 — tagged dataflow + per-block flag fast-path.
// 128 blocks x 1024 threads (16 waves). Block owns 16 units; wave owns 1 unit
// (3 gates x 2 batches = 6 dots of 2048). Weights in 48 VGPRs (packed bf16).
// Publish: 16 tagged u64 values per block (relaxed agent atomics), then
// __syncthreads (compiler drains vmcnt(0) before s_barrier), then ONE flag
// store flag[blk]=t+1. Readers poll only the 128 flags (128B-strided), then
// bulk-load the 4096 tagged values once and VERIFY tags (rare stale value ->
// individual spin). Correctness never depends on store-ack semantics.
// ---------------------------------------------------------------------------
#define GRU_NBLK 128
#define GRU_THREADS 1024

__global__ void __launch_bounds__(GRU_THREADS, 2) gru_kernel(
    const u32* __restrict__ whh_u32, const float* __restrict__ gi,
    const float* __restrict__ bhh, u64* __restrict__ hT,
    u32* __restrict__ flags, float* __restrict__ h_gru) {
    __shared__ __align__(16) float h_lds[2*DINNER];   // 16 KB: [b][j]
    int blk = blockIdx.x;
    int tid = threadIdx.x;
    int w = tid >> 6, lane = tid & 63;
    int j = blk*16 + w;          // the unit this wave owns

    // ---- preload weights: 3 gate rows for unit j, 16 u32 each ----
    u32 wr[3][16];
#pragma unroll
    for (int g = 0; g < 3; ++g) {
        const u32* row = whh_u32 + ((size_t)(g*DINNER + j))*(DINNER/2);
#pragma unroll
        for (int i = 0; i < 16; ++i) wr[g][i] = row[lane + 64*i];
    }
    // lanes 0,1 finalize batch b = lane
    int bme = lane & 1;
    float b_r = 0.f, b_z = 0.f, b_n = 0.f;
    if (lane < 2) { b_r = bhh[j]; b_z = bhh[DINNER+j]; b_n = bhh[2*DINNER+j]; }

    for (int t = 0; t < LSEQ; ++t) {
        int par = t & 1;
        // prefetch gi for this step (in flight during the flag poll)
        float ir = 0.f, iz = 0.f, inn = 0.f;
        if (lane < 2) {
            const float* g0 = gi + ((size_t)(bme*LSEQ + t))*(3*DINNER);
            ir = g0[j]; iz = g0[DINNER+j]; inn = g0[2*DINNER+j];
        }
        // ---- fast-path: poll per-block flags (128 flags, 1 lane each) ----
        if (lane < 8) {
            const u32* fp = flags + (w*8 + lane)*32;
            while (__hip_atomic_load(fp, __ATOMIC_RELAXED, __HIP_MEMORY_SCOPE_AGENT)
                   < (u32)t) {
                __builtin_amdgcn_s_sleep(1);
            }
        }
        __syncthreads();
        // ---- bulk stage S_t into LDS, verify tags (rare fallback spin) ----
        {
            const u64* src = hT + (size_t)par*(2*DINNER);
            u64 v[4];
#pragma unroll
            for (int r = 0; r < 4; ++r)
                v[r] = __hip_atomic_load(&src[tid + GRU_THREADS*r], __ATOMIC_RELAXED,
                                         __HIP_MEMORY_SCOPE_AGENT);
#pragma unroll
            for (int r = 0; r < 4; ++r) {
                int idx = tid + GRU_THREADS*r;
                while ((u32)(v[r] >> 32) != (u32)t) {   // stale (should be rare)
                    __builtin_amdgcn_s_sleep(1);
                    v[r] = __hip_atomic_load(&src[idx], __ATOMIC_RELAXED,
                                             __HIP_MEMORY_SCOPE_AGENT);
                }
                h_lds[idx] = __uint_as_float((u32)v[r]);
            }
        }
        __syncthreads();
        // ---- 6 dot products (3 gates x 2 batches) over 2048 ----
        float s[6];
#pragma unroll
        for (int q = 0; q < 6; ++q) s[q] = 0.f;
        const float2* hl0 = (const float2*)&h_lds[0];
        const float2* hl1 = (const float2*)&h_lds[DINNER];
#pragma unroll
        for (int i = 0; i < 16; ++i) {
            int k2 = lane + 64*i;
            float2 h0 = hl0[k2];
            float2 h1 = hl1[k2];
#pragma unroll
            for (int g = 0; g < 3; ++g) {
                u32 wv = wr[g][i];
                float we = __uint_as_float(wv << 16);
                float wo = __uint_as_float(wv & 0xFFFF0000u);
                s[g*2+0] += we*h0.x + wo*h0.y;
                s[g*2+1] += we*h1.x + wo*h1.y;
            }
        }
#pragma unroll
        for (int off = 32; off; off >>= 1)
#pragma unroll
            for (int q = 0; q < 6; ++q) s[q] += __shfl_xor(s[q], off, 64);

        if (lane < 2) {
            float sr = bme ? s[1] : s[0];
            float sz = bme ? s[3] : s[2];
            float sn = bme ? s[5] : s[4];
            float hp = h_lds[bme*DINNER + j];
            float r  = sigmoidf_(ir + sr + b_r);
            float uu = sigmoidf_(iz + sz + b_z);
            float nn = tanhf(inn + r*(sn + b_n));
            float hn = (1.f-uu)*nn + uu*hp;
            h_gru[((size_t)(bme*LSEQ + t))*DINNER + j] = hn;
            u64 pk = ((u64)(u32)(t+1) << 32) | (u64)__float_as_uint(hn);
            __hip_atomic_store(&hT[(size_t)(1-par)*(2*DINNER) + bme*DINNER + j],
                               pk, __ATOMIC_RELAXED, __HIP_MEMORY_SCOPE_AGENT);
        }
        // barrier: (a) protects h_lds WAR for next step, (b) compiler emits
        // s_waitcnt vmcnt(0) before s_barrier -> data stores drained before flag
        __syncthreads();
        if (tid == 0) {
            __hip_atomic_store(flags + blk*32, (u32)(t+1),
                               __ATOMIC_RELAXED, __HIP_MEMORY_SCOPE_AGENT);
        }
    }
}

// ---------------------------------------------------------------------------
// scaling = clip(softplus(clip(h_gru . WT_w + WT_b, -10, 10)), 0.1, 10)
// ---------------------------------------------------------------------------
__global__ void scaling_kernel(const float* __restrict__ h_gru, const float* __restrict__ WT_w,
                               const float* __restrict__ WT_b, const float* __restrict__ delta,
                               float* __restrict__ scaling, float* __restrict__ stg,
                               float* __restrict__ out_last) {
    __shared__ float red[4];
    int bt = blockIdx.x;
    int tid = threadIdx.x;
    const float* h = h_gru + (size_t)bt*DINNER;
    float p = 0.f;
    for (int k = tid; k < DINNER; k += 256) p += h[k]*WT_w[k];
#pragma unroll
    for (int off = 32; off; off >>= 1) p += __shfl_down(p, off, 64);
    if ((tid & 63) == 0) red[tid >> 6] = p;
    __syncthreads();
    if (tid == 0) {
        float v = red[0]+red[1]+red[2]+red[3] + WT_b[0];
        v = fminf(fmaxf(v, -10.f), 10.f);
        float sp = log1pf(__expf(v));
        sp = fminf(fmaxf(sp, 0.1f), 10.f);
        scaling[bt] = sp;
        stg[bt] = delta[bt]*sp;
        if ((bt & (LSEQ-1)) == LSEQ-1) out_last[bt >> 9] = sp;
    }
}

__global__ void intervals_kernel(const float* __restrict__ stg, float* __restrict__ intervals) {
    int idx = blockIdx.x*256 + threadIdx.x;
    if (idx < BT) {
        float v = stg[idx];
        if (idx & (LSEQ-1)) v -= stg[idx-1];
        intervals[idx] = v;
    }
}

__global__ void bdual_kernel(const float* __restrict__ content, const float* __restrict__ stg,
                             const float* __restrict__ Wtau_w, const float* __restrict__ B0,
                             float* __restrict__ B_dual) {
    int idx = blockIdx.x*256 + threadIdx.x;
    int n = idx & 15, bt = idx >> 4;
    float v = (n < EVENTD) ? content[bt*EVENTD + n] : stg[bt]*Wtau_w[n - EVENTD];
    B_dual[idx] = B0[n]*sigmoidf_(v);
}

// ---------------------------------------------------------------------------
// Fused selective scan + y epilogue. One thread per (b,d).
// ---------------------------------------------------------------------------
__global__ void scan_kernel(const float* __restrict__ base_dt, const float* __restrict__ intervals,
                            const float* __restrict__ B_dual, const float* __restrict__ x_dbl,
                            const float* __restrict__ x_conv, const float* __restrict__ xz,
                            const float* __restrict__ A_log, const float* __restrict__ D_param,
                            float* __restrict__ y_full) {
    int idx = blockIdx.x*256 + threadIdx.x;
    int d = idx & (DINNER-1);
    int b = idx >> 11;
    float Arow[DSTATE];
#pragma unroll
    for (int n = 0; n < DSTATE; ++n) Arow[n] = -__expf(A_log[d*DSTATE + n]);
    float Dd = D_param[d];
    float h[DSTATE];
#pragma unroll
    for (int n = 0; n < DSTATE; ++n) h[n] = 0.f;
    for (int t = 0; t < LSEQ; ++t) {
        size_t row = (size_t)b*LSEQ + t;
        float dt = intervals[row]*base_dt[row*DINNER + d];
        dt = fminf(fmaxf(dt, 1e-6f), 10.f);
        float xc = x_conv[row*DINNER + d];
        const float* Bd = B_dual + row*DSTATE;
        const float* Cc = x_dbl + row*96 + DTRANK + DSTATE;
        float y = 0.f;
#pragma unroll
        for (int n = 0; n < DSTATE; ++n) {
            float e = dt*Arow[n];
            e = fminf(fmaxf(e, -20.f), 20.f);
            float da = __expf(e);
            h[n] = da*h[n] + (dt*Bd[n])*xc;
            y += h[n]*Cc[n];
        }
        float z = xz[row*(2*DINNER) + DINNER + d];
        y_full[row*DINNER + d] = (y + xc*Dd) * (z*sigmoidf_(z));
    }
}

// ---------------------------------------------------------------------------
extern "C" void kernel_launch(void* const* d_in, const int* in_sizes, int n_in,
                              void* d_out, int out_size, void* d_ws, size_t ws_size,
                              hipStream_t stream) {
    const float* x         = (const float*)d_in[0];
    const float* delta     = (const float*)d_in[1];
    const float* in_proj_w = (const float*)d_in[2];
    const float* conv_w    = (const float*)d_in[3];
    const float* conv_b    = (const float*)d_in[4];
    const float* gru_wih   = (const float*)d_in[5];
    const float* gru_whh   = (const float*)d_in[6];
    const float* gru_bih   = (const float*)d_in[7];
    const float* gru_bhh   = (const float*)d_in[8];
    const float* WT_w      = (const float*)d_in[9];
    const float* WT_b      = (const float*)d_in[10];
    const float* Wc_w      = (const float*)d_in[11];
    const float* Wtau_w    = (const float*)d_in[12];
    const float* B0        = (const float*)d_in[13];
    const float* xproj_w   = (const float*)d_in[14];
    const float* dtproj_w  = (const float*)d_in[15];
    const float* dtproj_b  = (const float*)d_in[16];
    const float* A_log     = (const float*)d_in[17];
    const float* D_param   = (const float*)d_in[18];
    const float* outproj_w = (const float*)d_in[19];
    float* out = (float*)d_out;

    float* ws = (float*)d_ws;
    size_t off = 0;
    float* xz      = ws + off; off += (size_t)BT*2*DINNER;
    float* x_conv  = ws + off; off += (size_t)BT*DINNER;
    float* gi      = ws + off; off += (size_t)BT*3*DINNER;     // reused as y_full
    u16*   whh_bf  = (u16*)(ws + off); off += (size_t)3*DINNER*DINNER/2;
    float* h_gru   = ws + off; off += (size_t)BT*DINNER;
    float* base_dt = ws + off; off += (size_t)BT*DINNER;
    float* x_dbl   = ws + off; off += (size_t)BT*96;
    float* content = ws + off; off += (size_t)BT*16;
    float* B_dual  = ws + off; off += (size_t)BT*16;
    float* scaling = ws + off; off += BT;
    float* stg     = ws + off; off += BT;
    float* intervals = ws + off; off += BT;
    u64*   hT      = (u64*)(ws + off); off += 2*(2*2*DINNER);  // tagged h, 2 parities
    u32*   flags   = (u32*)(ws + off); off += GRU_NBLK*32;     // 128B-strided flags
    float* y_full  = gi;

    // init tagged-h buffers (tag=0 == S_0) and flags (0)
    hipMemsetAsync(hT, 0, (size_t)2*2*DINNER*sizeof(u64) + GRU_NBLK*32*sizeof(u32), stream);

    f32_to_bf16<<<4096, 256, 0, stream>>>(gru_whh, whh_bf, 3*DINNER*DINNER);

    // xz = x @ in_proj_w.T            (1024 x 4096, K=1024)
    gemm_nt<0><<<dim3(64,16), 256, 0, stream>>>(x, DMODEL, in_proj_w, nullptr, 0.f,
                                                xz, BT, 2*DINNER, DMODEL);
    conv_silu<<<(BT*DINNER)/256, 256, 0, stream>>>(xz, conv_w, conv_b, x_conv);

    // gi = x_conv @ gru_wih.T + bih   (1024 x 6144, K=2048)
    gemm_nt<0><<<dim3(96,16), 256, 0, stream>>>(x_conv, DINNER, gru_wih, gru_bih, 1.f,
                                                gi, BT, 3*DINNER, DINNER);

    gru_kernel<<<GRU_NBLK, GRU_THREADS, 0, stream>>>((const u32*)whh_bf, gi, gru_bhh,
                                                     hT, flags, h_gru);

    scaling_kernel<<<BT, 256, 0, stream>>>(h_gru, WT_w, WT_b, delta, scaling, stg,
                                           out + (size_t)BT*DMODEL);
    intervals_kernel<<<4, 256, 0, stream>>>(stg, intervals);

    // x_dbl = x_conv @ xproj_w.T      (1024 x 96, K=2048)
    gemm_nt<0><<<dim3(2,16), 256, 0, stream>>>(x_conv, DINNER, xproj_w, nullptr, 0.f,
                                               x_dbl, BT, 96, DINNER);
    // base_dt = softplus(dt_low @ dtproj_w.T + 2*dtproj_b)
    gemm_nt<1><<<dim3(32,16), 256, 0, stream>>>(x_dbl, 96, dtproj_w, dtproj_b, 2.f,
                                                base_dt, BT, DINNER, DTRANK);
    // content = x_conv @ Wc_w.T       (1024 x 10, K=2048)
    gemm_nt<0><<<dim3(1,16), 256, 0, stream>>>(x_conv, DINNER, Wc_w, nullptr, 0.f,
                                               content, BT, EVENTD, DINNER);
    bdual_kernel<<<(BT*16)/256, 256, 0, stream>>>(content, stg, Wtau_w, B0, B_dual);

    scan_kernel<<<(BATCH*DINNER)/256, 256, 0, stream>>>(base_dt, intervals, B_dual, x_dbl,
                                                        x_conv, xz, A_log, D_param, y_full);

    // out = y_full @ outproj_w.T      (1024 x 1024, K=2048)
    gemm_nt<0><<<dim3(16,16), 256, 0, stream>>>(y_full, DINNER, outproj_w, nullptr, 0.f,
                                                out, BT, DMODEL, DINNER);
}

// Round 4
// 5460.613 us; speedup vs baseline: 2.5371x; 1.0526x over previous
//
#include <hip/hip_runtime.h>
#include <hip/hip_bf16.h>

// Sizes (fixed for this problem)
#define BATCH 2
#define LSEQ 512
#define DMODEL 1024
#define DINNER 2048
#define DSTATE 16
#define DTRANK 64
#define DCONV 4
#define EVENTD 10
#define TIMED 6
#define BT (BATCH*LSEQ)   // 1024

typedef unsigned int u32;
typedef unsigned short u16;
typedef unsigned long long u64;
typedef __attribute__((ext_vector_type(8))) short short8;
typedef __attribute__((ext_vector_type(4))) float f32x4;

__device__ __forceinline__ float sigmoidf_(float x) { return 1.f/(1.f+__expf(-x)); }
__device__ __forceinline__ u16 to_bf16_(float f) {
    u32 u = __float_as_uint(f);
    return (u16)((u + 0x7FFFu + ((u >> 16) & 1u)) >> 16);
}

// ---------------------------------------------------------------------------
// f32 -> bf16 (RNE)
// ---------------------------------------------------------------------------
__global__ void f32_to_bf16(const float* __restrict__ src, u16* __restrict__ dst, int n) {
    for (int i = blockIdx.x*blockDim.x + threadIdx.x; i < n; i += gridDim.x*blockDim.x)
        dst[i] = to_bf16_(src[i]);
}

// ---------------------------------------------------------------------------
// bf16 MFMA GEMM: C[M,N] = A[M,K] @ W[N,K]^T (+bias). 64x64 tile, 256 thr,
// 4 waves; wave w owns m-strip w*16, computes 4 16x16 accs across N.
// LDS row stride 40 u16 (80B): frag ds_read_b128 <=2-way bank conflict.
// M%64==0, N%64==0, K%32==0.
// ---------------------------------------------------------------------------
#define LSTR 40
template<int HAS_BIAS>
__global__ void __launch_bounds__(256) gemm_mfma_nt(
    const u16* __restrict__ A, const u16* __restrict__ W,
    const float* __restrict__ bias,
    float* __restrict__ C, int M, int N, int K) {
    __shared__ __align__(16) u16 Asl[64*LSTR];
    __shared__ __align__(16) u16 Bsl[64*LSTR];
    int tid = threadIdx.x;
    int wave = tid >> 6, lane = tid & 63;
    int m0 = blockIdx.y*64, n0 = blockIdx.x*64;
    int mstrip = wave*16;
    int fr = lane & 15, quad = lane >> 4;
    f32x4 acc[4];
#pragma unroll
    for (int nt = 0; nt < 4; ++nt) acc[nt] = (f32x4){0.f,0.f,0.f,0.f};

    int srow = tid >> 2, sk = (tid & 3)*8;   // staging: row 0..63, k-seg 0..3
    const u16* Ap = A + (size_t)(m0+srow)*K + sk;
    const u16* Wp = W + (size_t)(n0+srow)*K + sk;
    for (int k0 = 0; k0 < K; k0 += 32) {
        uint4 av = *(const uint4*)(Ap + k0);
        uint4 bv = *(const uint4*)(Wp + k0);
        __syncthreads();
        *(uint4*)&Asl[srow*LSTR + sk] = av;
        *(uint4*)&Bsl[srow*LSTR + sk] = bv;
        __syncthreads();
        short8 af = *(const short8*)&Asl[(mstrip+fr)*LSTR + quad*8];
#pragma unroll
        for (int nt = 0; nt < 4; ++nt) {
            short8 bf = *(const short8*)&Bsl[(nt*16+fr)*LSTR + quad*8];
            acc[nt] = __builtin_amdgcn_mfma_f32_16x16x32_bf16(af, bf, acc[nt], 0, 0, 0);
        }
    }
    // C/D layout (m89-verified): col = lane&15, row = (lane>>4)*4 + reg
#pragma unroll
    for (int nt = 0; nt < 4; ++nt) {
        int col = n0 + nt*16 + fr;
        float bb = HAS_BIAS ? bias[col] : 0.f;
#pragma unroll
        for (int r = 0; r < 4; ++r) {
            int row = m0 + mstrip + quad*4 + r;
            C[(size_t)row*N + col] = acc[nt][r] + bb;
        }
    }
}

// ---------------------------------------------------------------------------
// Generic fp32 GEMM (kept for small/precision-sensitive projections)
// ---------------------------------------------------------------------------
template<int ACT>
__global__ void __launch_bounds__(256) gemm_nt(
    const float* __restrict__ A, int lda,
    const float* __restrict__ W,
    const float* __restrict__ bias, float bias_scale,
    float* __restrict__ C, int M, int N, int K) {
    __shared__ __align__(16) float As[16*72];
    __shared__ __align__(16) float Ws[16*72];
    int tid = threadIdx.x;
    int tx = tid & 15, ty = tid >> 4;
    int m0 = blockIdx.y*64, n0 = blockIdx.x*64;
    float acc[4][4];
#pragma unroll
    for (int i = 0; i < 4; ++i)
#pragma unroll
        for (int j = 0; j < 4; ++j) acc[i][j] = 0.f;
    int kq = tid & 15;
    int mq = tid >> 4;
    for (int k0 = 0; k0 < K; k0 += 16) {
#pragma unroll
        for (int r = 0; r < 4; ++r) {
            int m = mq + r*16;
            As[kq*72 + m] = A[(size_t)(m0+m)*lda + k0 + kq];
            int n = n0 + m;
            Ws[kq*72 + m] = (n < N) ? W[(size_t)n*K + k0 + kq] : 0.f;
        }
        __syncthreads();
#pragma unroll
        for (int kk = 0; kk < 16; ++kk) {
            float4 a4 = *(const float4*)&As[kk*72 + ty*4];
            float4 b4 = *(const float4*)&Ws[kk*72 + tx*4];
            float av[4] = {a4.x, a4.y, a4.z, a4.w};
            float bv[4] = {b4.x, b4.y, b4.z, b4.w};
#pragma unroll
            for (int i = 0; i < 4; ++i)
#pragma unroll
                for (int j = 0; j < 4; ++j) acc[i][j] += av[i]*bv[j];
        }
        __syncthreads();
    }
#pragma unroll
    for (int i = 0; i < 4; ++i) {
        int m = m0 + ty*4 + i;
#pragma unroll
        for (int j = 0; j < 4; ++j) {
            int n = n0 + tx*4 + j;
            if (n < N) {
                float v = acc[i][j];
                if (bias) v += bias_scale*bias[n];
                if (ACT == 1) v = (v > 20.f) ? v : log1pf(__expf(v));
                C[(size_t)m*N + n] = v;
            }
        }
    }
}

// ---------------------------------------------------------------------------
// Causal depthwise conv (width 4) + SiLU. Dual-writes fp32 + bf16.
// ---------------------------------------------------------------------------
__global__ void conv_silu(const float* __restrict__ xz, const float* __restrict__ conv_w,
                          const float* __restrict__ conv_b, float* __restrict__ x_conv,
                          u16* __restrict__ x_conv_bf) {
    int idx = blockIdx.x*blockDim.x + threadIdx.x;
    int d = idx & (DINNER-1);
    int bt = idx >> 11;
    int t = bt & (LSEQ-1); int b = bt >> 9;
    float acc = conv_b[d];
#pragma unroll
    for (int k = 0; k < DCONV; ++k) {
        int tt = t - (DCONV-1) + k;
        if (tt >= 0) acc += xz[((size_t)(b*LSEQ+tt))*(2*DINNER) + d] * conv_w[d*DCONV + k];
    }
    float v = acc * sigmoidf_(acc);
    x_conv[idx] = v;
    x_conv_bf[idx] = to_bf16_(v);
}

// ---------------------------------------------------------------------------
// Persistent GRU scan v4 — pure tagged dataflow (no flags).
// 128 blocks x 1024 threads. Wave owns 1 unit (3 gates x 2 batches).
// Publish: tagged u64 (tag<<32|f32) relaxed agent atomics. Readers poll the
// values directly; stale values re-polled CONCURRENTLY per pass with backoff.
// ---------------------------------------------------------------------------
#define GRU_NBLK 128
#define GRU_THREADS 1024

__global__ void __launch_bounds__(GRU_THREADS, 2) gru_kernel(
    const u32* __restrict__ whh_u32, const float* __restrict__ gi,
    const float* __restrict__ bhh, u64* __restrict__ hT,
    float* __restrict__ h_gru) {
    __shared__ __align__(16) float h_lds[2*DINNER];   // 16 KB: [b][j]
    int blk = blockIdx.x;
    int tid = threadIdx.x;
    int w = tid >> 6, lane = tid & 63;
    int j = blk*16 + w;          // the unit this wave owns

    // preload weights: 3 gate rows for unit j, 16 u32 (bf16-pairs) each
    u32 wr[3][16];
#pragma unroll
    for (int g = 0; g < 3; ++g) {
        const u32* row = whh_u32 + ((size_t)(g*DINNER + j))*(DINNER/2);
#pragma unroll
        for (int i = 0; i < 16; ++i) wr[g][i] = row[lane + 64*i];
    }
    int bme = lane & 1;
    float b_r = 0.f, b_z = 0.f, b_n = 0.f;
    if (lane < 2) { b_r = bhh[j]; b_z = bhh[DINNER+j]; b_n = bhh[2*DINNER+j]; }

    for (int t = 0; t < LSEQ; ++t) {
        int par = t & 1;
        // prefetch gi (in flight during the poll)
        float ir = 0.f, iz = 0.f, inn = 0.f;
        if (lane < 2) {
            const float* g0 = gi + ((size_t)(bme*LSEQ + t))*(3*DINNER);
            ir = g0[j]; iz = g0[DINNER+j]; inn = g0[2*DINNER+j];
        }
        // ---- poll + stage S_t (grouped concurrent re-poll of stale values) ----
        {
            const u64* src = hT + (size_t)par*(2*DINNER);
            u64 v[4];
#pragma unroll
            for (int r = 0; r < 4; ++r)
                v[r] = __hip_atomic_load(&src[tid + GRU_THREADS*r], __ATOMIC_RELAXED,
                                         __HIP_MEMORY_SCOPE_AGENT);
            int pass = 0;
            while (true) {
                u32 bad = 0;
#pragma unroll
                for (int r = 0; r < 4; ++r)
                    if ((u32)(v[r] >> 32) != (u32)t) bad |= (1u << r);
                if (!bad) break;
                if (pass++) __builtin_amdgcn_s_sleep(1);
#pragma unroll
                for (int r = 0; r < 4; ++r)
                    if (bad & (1u << r))
                        v[r] = __hip_atomic_load(&src[tid + GRU_THREADS*r], __ATOMIC_RELAXED,
                                                 __HIP_MEMORY_SCOPE_AGENT);
            }
#pragma unroll
            for (int r = 0; r < 4; ++r)
                h_lds[tid + GRU_THREADS*r] = __uint_as_float((u32)v[r]);
        }
        __syncthreads();
        // ---- 6 dot products (3 gates x 2 batches) over 2048 ----
        float s[6];
#pragma unroll
        for (int q = 0; q < 6; ++q) s[q] = 0.f;
        const float2* hl0 = (const float2*)&h_lds[0];
        const float2* hl1 = (const float2*)&h_lds[DINNER];
#pragma unroll
        for (int i = 0; i < 16; ++i) {
            int k2 = lane + 64*i;
            float2 h0 = hl0[k2];
            float2 h1 = hl1[k2];
#pragma unroll
            for (int g = 0; g < 3; ++g) {
                u32 wv = wr[g][i];
                float we = __uint_as_float(wv << 16);
                float wo = __uint_as_float(wv & 0xFFFF0000u);
                s[g*2+0] += we*h0.x + wo*h0.y;
                s[g*2+1] += we*h1.x + wo*h1.y;
            }
        }
#pragma unroll
        for (int off = 32; off; off >>= 1)
#pragma unroll
            for (int q = 0; q < 6; ++q) s[q] += __shfl_xor(s[q], off, 64);

        if (lane < 2) {
            float sr = bme ? s[1] : s[0];
            float sz = bme ? s[3] : s[2];
            float sn = bme ? s[5] : s[4];
            float hp = h_lds[bme*DINNER + j];
            float r  = sigmoidf_(ir + sr + b_r);
            float uu = sigmoidf_(iz + sz + b_z);
            float nn = tanhf(inn + r*(sn + b_n));
            float hn = (1.f-uu)*nn + uu*hp;
            h_gru[((size_t)(bme*LSEQ + t))*DINNER + j] = hn;
            u64 pk = ((u64)(u32)(t+1) << 32) | (u64)__float_as_uint(hn);
            __hip_atomic_store(&hT[(size_t)(1-par)*(2*DINNER) + bme*DINNER + j],
                               pk, __ATOMIC_RELAXED, __HIP_MEMORY_SCOPE_AGENT);
        }
        __syncthreads();   // WAR: all waves done reading h_lds before next staging
    }
}

// ---------------------------------------------------------------------------
// scaling = clip(softplus(clip(h_gru . WT_w + WT_b, -10, 10)), 0.1, 10)
// ---------------------------------------------------------------------------
__global__ void scaling_kernel(const float* __restrict__ h_gru, const float* __restrict__ WT_w,
                               const float* __restrict__ WT_b, const float* __restrict__ delta,
                               float* __restrict__ scaling, float* __restrict__ stg,
                               float* __restrict__ out_last) {
    __shared__ float red[4];
    int bt = blockIdx.x;
    int tid = threadIdx.x;
    const float* h = h_gru + (size_t)bt*DINNER;
    float p = 0.f;
    for (int k = tid; k < DINNER; k += 256) p += h[k]*WT_w[k];
#pragma unroll
    for (int off = 32; off; off >>= 1) p += __shfl_down(p, off, 64);
    if ((tid & 63) == 0) red[tid >> 6] = p;
    __syncthreads();
    if (tid == 0) {
        float v = red[0]+red[1]+red[2]+red[3] + WT_b[0];
        v = fminf(fmaxf(v, -10.f), 10.f);
        float sp = log1pf(__expf(v));
        sp = fminf(fmaxf(sp, 0.1f), 10.f);
        scaling[bt] = sp;
        stg[bt] = delta[bt]*sp;
        if ((bt & (LSEQ-1)) == LSEQ-1) out_last[bt >> 9] = sp;
    }
}

__global__ void intervals_kernel(const float* __restrict__ stg, float* __restrict__ intervals) {
    int idx = blockIdx.x*256 + threadIdx.x;
    if (idx < BT) {
        float v = stg[idx];
        if (idx & (LSEQ-1)) v -= stg[idx-1];
        intervals[idx] = v;
    }
}

__global__ void bdual_kernel(const float* __restrict__ content, const float* __restrict__ stg,
                             const float* __restrict__ Wtau_w, const float* __restrict__ B0,
                             float* __restrict__ B_dual) {
    int idx = blockIdx.x*256 + threadIdx.x;
    int n = idx & 15, bt = idx >> 4;
    float v = (n < EVENTD) ? content[bt*EVENTD + n] : stg[bt]*Wtau_w[n - EVENTD];
    B_dual[idx] = B0[n]*sigmoidf_(v);
}

// ---------------------------------------------------------------------------
// Fused selective scan + y epilogue. One thread per (b,d). Dual-writes y bf16.
// ---------------------------------------------------------------------------
__global__ void scan_kernel(const float* __restrict__ base_dt, const float* __restrict__ intervals,
                            const float* __restrict__ B_dual, const float* __restrict__ x_dbl,
                            const float* __restrict__ x_conv, const float* __restrict__ xz,
                            const float* __restrict__ A_log, const float* __restrict__ D_param,
                            u16* __restrict__ y_bf) {
    int idx = blockIdx.x*256 + threadIdx.x;
    int d = idx & (DINNER-1);
    int b = idx >> 11;
    float Arow[DSTATE];
#pragma unroll
    for (int n = 0; n < DSTATE; ++n) Arow[n] = -__expf(A_log[d*DSTATE + n]);
    float Dd = D_param[d];
    float h[DSTATE];
#pragma unroll
    for (int n = 0; n < DSTATE; ++n) h[n] = 0.f;
    for (int t = 0; t < LSEQ; ++t) {
        size_t row = (size_t)b*LSEQ + t;
        float dt = intervals[row]*base_dt[row*DINNER + d];
        dt = fminf(fmaxf(dt, 1e-6f), 10.f);
        float xc = x_conv[row*DINNER + d];
        const float* Bd = B_dual + row*DSTATE;
        const float* Cc = x_dbl + row*96 + DTRANK + DSTATE;
        float y = 0.f;
#pragma unroll
        for (int n = 0; n < DSTATE; ++n) {
            float e = dt*Arow[n];
            e = fminf(fmaxf(e, -20.f), 20.f);
            float da = __expf(e);
            h[n] = da*h[n] + (dt*Bd[n])*xc;
            y += h[n]*Cc[n];
        }
        float z = xz[row*(2*DINNER) + DINNER + d];
        y_bf[row*DINNER + d] = to_bf16_((y + xc*Dd) * (z*sigmoidf_(z)));
    }
}

// ---------------------------------------------------------------------------
extern "C" void kernel_launch(void* const* d_in, const int* in_sizes, int n_in,
                              void* d_out, int out_size, void* d_ws, size_t ws_size,
                              hipStream_t stream) {
    const float* x         = (const float*)d_in[0];
    const float* delta     = (const float*)d_in[1];
    const float* in_proj_w = (const float*)d_in[2];
    const float* conv_w    = (const float*)d_in[3];
    const float* conv_b    = (const float*)d_in[4];
    const float* gru_wih   = (const float*)d_in[5];
    const float* gru_whh   = (const float*)d_in[6];
    const float* gru_bih   = (const float*)d_in[7];
    const float* gru_bhh   = (const float*)d_in[8];
    const float* WT_w      = (const float*)d_in[9];
    const float* WT_b      = (const float*)d_in[10];
    const float* Wc_w      = (const float*)d_in[11];
    const float* Wtau_w    = (const float*)d_in[12];
    const float* B0        = (const float*)d_in[13];
    const float* xproj_w   = (const float*)d_in[14];
    const float* dtproj_w  = (const float*)d_in[15];
    const float* dtproj_b  = (const float*)d_in[16];
    const float* A_log     = (const float*)d_in[17];
    const float* D_param   = (const float*)d_in[18];
    const float* outproj_w = (const float*)d_in[19];
    float* out = (float*)d_out;

    float* ws = (float*)d_ws;
    size_t off = 0;
    float* xz        = ws + off; off += (size_t)BT*2*DINNER;          // 4.19M
    float* x_conv    = ws + off; off += (size_t)BT*DINNER;            // 2.10M
    float* gi        = ws + off; off += (size_t)BT*3*DINNER;          // 6.29M
    u16*   whh_bf    = (u16*)(ws + off); off += (size_t)3*DINNER*DINNER/2;  // 3.15M f
    float* h_gru     = ws + off; off += (size_t)BT*DINNER;            // 2.10M
    float* base_dt   = ws + off; off += (size_t)BT*DINNER;            // 2.10M
    float* x_dbl     = ws + off; off += (size_t)BT*96;
    float* content   = ws + off; off += (size_t)BT*16;
    float* B_dual    = ws + off; off += (size_t)BT*16;
    float* scaling   = ws + off; off += BT;
    float* stg       = ws + off; off += BT;
    float* intervals = ws + off; off += BT;
    u64*   hT        = (u64*)(ws + off); off += 2*(2*2*DINNER);       // tagged h
    u16*   x_bf      = (u16*)(ws + off); off += (size_t)BT*DMODEL/2;
    u16*   inprojw_bf= (u16*)(ws + off); off += (size_t)2*DINNER*DMODEL/2;
    u16*   wih_bf    = (u16*)(ws + off); off += (size_t)3*DINNER*DINNER/2;
    u16*   outw_bf   = (u16*)(ws + off); off += (size_t)DMODEL*DINNER/2;
    u16*   xconv_bf  = (u16*)(ws + off); off += (size_t)BT*DINNER/2;
    u16*   y_bf      = (u16*)(ws + off); off += (size_t)BT*DINNER/2;
    // ~103 MB total

    // init tagged-h buffers (tag=0 == S_0 ready, h=0)
    hipMemsetAsync(hT, 0, (size_t)2*2*DINNER*sizeof(u64), stream);

    // bf16 conversions
    f32_to_bf16<<<4096, 256, 0, stream>>>(gru_whh, whh_bf, 3*DINNER*DINNER);
    f32_to_bf16<<<4096, 256, 0, stream>>>(in_proj_w, inprojw_bf, 2*DINNER*DMODEL);
    f32_to_bf16<<<4096, 256, 0, stream>>>(gru_wih, wih_bf, 3*DINNER*DINNER);
    f32_to_bf16<<<2048, 256, 0, stream>>>(outproj_w, outw_bf, DMODEL*DINNER);
    f32_to_bf16<<<2048, 256, 0, stream>>>(x, x_bf, BT*DMODEL);

    // xz = x @ in_proj_w.T            (1024 x 4096, K=1024)  [MFMA bf16]
    gemm_mfma_nt<0><<<dim3(64,16), 256, 0, stream>>>(x_bf, inprojw_bf, nullptr,
                                                     xz, BT, 2*DINNER, DMODEL);
    conv_silu<<<(BT*DINNER)/256, 256, 0, stream>>>(xz, conv_w, conv_b, x_conv, xconv_bf);

    // gi = x_conv @ gru_wih.T + bih   (1024 x 6144, K=2048)  [MFMA bf16]
    gemm_mfma_nt<1><<<dim3(96,16), 256, 0, stream>>>(xconv_bf, wih_bf, gru_bih,
                                                     gi, BT, 3*DINNER, DINNER);

    gru_kernel<<<GRU_NBLK, GRU_THREADS, 0, stream>>>((const u32*)whh_bf, gi, gru_bhh,
                                                     hT, h_gru);

    scaling_kernel<<<BT, 256, 0, stream>>>(h_gru, WT_w, WT_b, delta, scaling, stg,
                                           out + (size_t)BT*DMODEL);
    intervals_kernel<<<4, 256, 0, stream>>>(stg, intervals);

    // x_dbl = x_conv @ xproj_w.T      (1024 x 96, K=2048)  [fp32, precision path]
    gemm_nt<0><<<dim3(2,16), 256, 0, stream>>>(x_conv, DINNER, xproj_w, nullptr, 0.f,
                                               x_dbl, BT, 96, DINNER);
    // base_dt = softplus(dt_low @ dtproj_w.T + 2*dtproj_b)  [fp32]
    gemm_nt<1><<<dim3(32,16), 256, 0, stream>>>(x_dbl, 96, dtproj_w, dtproj_b, 2.f,
                                                base_dt, BT, DINNER, DTRANK);
    // content = x_conv @ Wc_w.T       (1024 x 10, K=2048)  [fp32]
    gemm_nt<0><<<dim3(1,16), 256, 0, stream>>>(x_conv, DINNER, Wc_w, nullptr, 0.f,
                                               content, BT, EVENTD, DINNER);
    bdual_kernel<<<(BT*16)/256, 256, 0, stream>>>(content, stg, Wtau_w, B0, B_dual);

    scan_kernel<<<(BATCH*DINNER)/256, 256, 0, stream>>>(base_dt, intervals, B_dual, x_dbl,
                                                        x_conv, xz, A_log, D_param, y_bf);

    // out = y @ outproj_w.T           (1024 x 1024, K=2048)  [MFMA bf16]
    gemm_mfma_nt<0><<<dim3(16,16), 256, 0, stream>>>(y_bf, outw_bf, nullptr,
                                                     out, BT, DMODEL, DINNER);
}

// Round 5
// 2726.795 us; speedup vs baseline: 5.0808x; 2.0026x over previous
//
#include <hip/hip_runtime.h>
#include <hip/hip_bf16.h>

// Sizes (fixed for this problem)
#define BATCH 2
#define LSEQ 512
#define DMODEL 1024
#define DINNER 2048
#define DSTATE 16
#define DTRANK 64
#define DCONV 4
#define EVENTD 10
#define TIMED 6
#define BT (BATCH*LSEQ)   // 1024

typedef unsigned int u32;
typedef unsigned short u16;
typedef unsigned long long u64;
typedef __attribute__((ext_vector_type(8))) short short8;
typedef __attribute__((ext_vector_type(4))) float f32x4;
typedef _Float16 h2_t __attribute__((ext_vector_type(2)));

__device__ __forceinline__ float sigmoidf_(float x) { return 1.f/(1.f+__expf(-x)); }
__device__ __forceinline__ u16 to_bf16_(float f) {
    u32 u = __float_as_uint(f);
    return (u16)((u + 0x7FFFu + ((u >> 16) & 1u)) >> 16);
}
__device__ __forceinline__ u32 pack_h2(float a, float b) {
    _Float16 ha = (_Float16)a, hb = (_Float16)b;
    u16 ua, ub;
    __builtin_memcpy(&ua, &ha, 2);
    __builtin_memcpy(&ub, &hb, 2);
    return (u32)ua | ((u32)ub << 16);
}

// ---------------------------------------------------------------------------
// f32 -> bf16 (RNE)
// ---------------------------------------------------------------------------
__global__ void f32_to_bf16(const float* __restrict__ src, u16* __restrict__ dst, int n) {
    for (int i = blockIdx.x*blockDim.x + threadIdx.x; i < n; i += gridDim.x*blockDim.x)
        dst[i] = to_bf16_(src[i]);
}

// f32 pairs -> packed fp16 pairs (low 16 = even index)
__global__ void f32_to_h2(const float* __restrict__ src, u32* __restrict__ dst, int npairs) {
    for (int i = blockIdx.x*blockDim.x + threadIdx.x; i < npairs; i += gridDim.x*blockDim.x) {
        float2 v = ((const float2*)src)[i];
        dst[i] = pack_h2(v.x, v.y);
    }
}

// ---------------------------------------------------------------------------
// bf16 MFMA GEMM: C[M,N] = A[M,K] @ W[N,K]^T (+bias). 64x64 tile, 256 thr.
// ---------------------------------------------------------------------------
#define LSTR 40
template<int HAS_BIAS>
__global__ void __launch_bounds__(256) gemm_mfma_nt(
    const u16* __restrict__ A, const u16* __restrict__ W,
    const float* __restrict__ bias,
    float* __restrict__ C, int M, int N, int K) {
    __shared__ __align__(16) u16 Asl[64*LSTR];
    __shared__ __align__(16) u16 Bsl[64*LSTR];
    int tid = threadIdx.x;
    int wave = tid >> 6, lane = tid & 63;
    int m0 = blockIdx.y*64, n0 = blockIdx.x*64;
    int mstrip = wave*16;
    int fr = lane & 15, quad = lane >> 4;
    f32x4 acc[4];
#pragma unroll
    for (int nt = 0; nt < 4; ++nt) acc[nt] = (f32x4){0.f,0.f,0.f,0.f};

    int srow = tid >> 2, sk = (tid & 3)*8;
    const u16* Ap = A + (size_t)(m0+srow)*K + sk;
    const u16* Wp = W + (size_t)(n0+srow)*K + sk;
    for (int k0 = 0; k0 < K; k0 += 32) {
        uint4 av = *(const uint4*)(Ap + k0);
        uint4 bv = *(const uint4*)(Wp + k0);
        __syncthreads();
        *(uint4*)&Asl[srow*LSTR + sk] = av;
        *(uint4*)&Bsl[srow*LSTR + sk] = bv;
        __syncthreads();
        short8 af = *(const short8*)&Asl[(mstrip+fr)*LSTR + quad*8];
#pragma unroll
        for (int nt = 0; nt < 4; ++nt) {
            short8 bf = *(const short8*)&Bsl[(nt*16+fr)*LSTR + quad*8];
            acc[nt] = __builtin_amdgcn_mfma_f32_16x16x32_bf16(af, bf, acc[nt], 0, 0, 0);
        }
    }
#pragma unroll
    for (int nt = 0; nt < 4; ++nt) {
        int col = n0 + nt*16 + fr;
        float bb = HAS_BIAS ? bias[col] : 0.f;
#pragma unroll
        for (int r = 0; r < 4; ++r) {
            int row = m0 + mstrip + quad*4 + r;
            C[(size_t)row*N + col] = acc[nt][r] + bb;
        }
    }
}

// ---------------------------------------------------------------------------
// Generic fp32 GEMM (precision-sensitive projections)
// ---------------------------------------------------------------------------
template<int ACT>
__global__ void __launch_bounds__(256) gemm_nt(
    const float* __restrict__ A, int lda,
    const float* __restrict__ W,
    const float* __restrict__ bias, float bias_scale,
    float* __restrict__ C, int M, int N, int K) {
    __shared__ __align__(16) float As[16*72];
    __shared__ __align__(16) float Ws[16*72];
    int tid = threadIdx.x;
    int tx = tid & 15, ty = tid >> 4;
    int m0 = blockIdx.y*64, n0 = blockIdx.x*64;
    float acc[4][4];
#pragma unroll
    for (int i = 0; i < 4; ++i)
#pragma unroll
        for (int j = 0; j < 4; ++j) acc[i][j] = 0.f;
    int kq = tid & 15;
    int mq = tid >> 4;
    for (int k0 = 0; k0 < K; k0 += 16) {
#pragma unroll
        for (int r = 0; r < 4; ++r) {
            int m = mq + r*16;
            As[kq*72 + m] = A[(size_t)(m0+m)*lda + k0 + kq];
            int n = n0 + m;
            Ws[kq*72 + m] = (n < N) ? W[(size_t)n*K + k0 + kq] : 0.f;
        }
        __syncthreads();
#pragma unroll
        for (int kk = 0; kk < 16; ++kk) {
            float4 a4 = *(const float4*)&As[kk*72 + ty*4];
            float4 b4 = *(const float4*)&Ws[kk*72 + tx*4];
            float av[4] = {a4.x, a4.y, a4.z, a4.w};
            float bv[4] = {b4.x, b4.y, b4.z, b4.w};
#pragma unroll
            for (int i = 0; i < 4; ++i)
#pragma unroll
                for (int j = 0; j < 4; ++j) acc[i][j] += av[i]*bv[j];
        }
        __syncthreads();
    }
#pragma unroll
    for (int i = 0; i < 4; ++i) {
        int m = m0 + ty*4 + i;
#pragma unroll
        for (int j = 0; j < 4; ++j) {
            int n = n0 + tx*4 + j;
            if (n < N) {
                float v = acc[i][j];
                if (bias) v += bias_scale*bias[n];
                if (ACT == 1) v = (v > 20.f) ? v : log1pf(__expf(v));
                C[(size_t)m*N + n] = v;
            }
        }
    }
}

// ---------------------------------------------------------------------------
// Causal depthwise conv (width 4) + SiLU. Dual-writes fp32 + bf16.
// ---------------------------------------------------------------------------
__global__ void conv_silu(const float* __restrict__ xz, const float* __restrict__ conv_w,
                          const float* __restrict__ conv_b, float* __restrict__ x_conv,
                          u16* __restrict__ x_conv_bf) {
    int idx = blockIdx.x*blockDim.x + threadIdx.x;
    int d = idx & (DINNER-1);
    int bt = idx >> 11;
    int t = bt & (LSEQ-1); int b = bt >> 9;
    float acc = conv_b[d];
#pragma unroll
    for (int k = 0; k < DCONV; ++k) {
        int tt = t - (DCONV-1) + k;
        if (tt >= 0) acc += xz[((size_t)(b*LSEQ+tt))*(2*DINNER) + d] * conv_w[d*DCONV + k];
    }
    float v = acc * sigmoidf_(acc);
    x_conv[idx] = v;
    x_conv_bf[idx] = to_bf16_(v);
}

// ---------------------------------------------------------------------------
// Persistent GRU scan v5 — fp16 fdot2 + batch-split chains + paired tags.
// 256 blocks x 1024 threads (16 waves), all 256 CUs. Chain = batch (b=blk>>7),
// 128 blocks per chain. Block owns 16 units of its batch; wave owns 1 unit
// (3 gates, dot length 2048 via v_dot2_f32_f16). Weights: fp16 pairs in 48
// VGPRs. Exchange: 1024 u64 per chain, each = (tag32 | 2xfp16); ONE tagged
// atomic load per thread per step. Own-unit h kept exact fp32 in lane 0
// (no rounding feedback through the recurrence's self path).
// ---------------------------------------------------------------------------
#define GRU_NBLK 256
#define GRU_THREADS 1024

__global__ void __launch_bounds__(GRU_THREADS, 1) gru_kernel(
    const u32* __restrict__ whh_h2, const float* __restrict__ gi,
    const float* __restrict__ bhh, u64* __restrict__ hT,
    float* __restrict__ h_gru) {
    __shared__ u32 h2[DINNER/2];    // 4 KB: fp16 pair per 2 units
    __shared__ float pub[16];
    int blk = blockIdx.x;
    int tid = threadIdx.x;
    int w = tid >> 6, lane = tid & 63;
    int b = blk >> 7;               // chain = batch
    int j0 = (blk & 127) << 4;
    int j = j0 + w;                 // unit this wave owns

    // preload fp16-pair weights: 3 gate rows, 16 u32 each (48 VGPRs)
    u32 wr[3][16];
#pragma unroll
    for (int g = 0; g < 3; ++g) {
        const u32* row = whh_h2 + ((size_t)(g*DINNER + j))*(DINNER/2);
#pragma unroll
        for (int i = 0; i < 16; ++i) wr[g][i] = row[lane + 64*i];
    }
    float b_r = 0.f, b_z = 0.f, b_n = 0.f, hp = 0.f;
    if (lane == 0) { b_r = bhh[j]; b_z = bhh[DINNER+j]; b_n = bhh[2*DINNER+j]; }

    u64* my = hT + (size_t)(b*2)*(DINNER/2);           // this chain's buffers
    const float* gib = gi + (size_t)b*LSEQ*(3*DINNER);

    for (int t = 0; t < LSEQ; ++t) {
        int par = t & 1;
        // prefetch gi (in flight during the poll)
        float ir = 0.f, iz = 0.f, inn = 0.f;
        if (lane == 0) {
            const float* g0 = gib + (size_t)t*(3*DINNER);
            ir = g0[j]; iz = g0[DINNER+j]; inn = g0[2*DINNER+j];
        }
        // ---- poll + stage: ONE tagged u64 per thread ----
        {
            const u64* src = my + par*(DINNER/2);
            u64 v = __hip_atomic_load(&src[tid], __ATOMIC_RELAXED,
                                      __HIP_MEMORY_SCOPE_AGENT);
            while ((u32)(v >> 32) != (u32)t) {
                __builtin_amdgcn_s_sleep(1);
                v = __hip_atomic_load(&src[tid], __ATOMIC_RELAXED,
                                      __HIP_MEMORY_SCOPE_AGENT);
            }
            h2[tid] = (u32)v;
        }
        __syncthreads();
        // ---- 3 dots of 2048 via v_dot2_f32_f16 ----
        float s0 = 0.f, s1 = 0.f, s2 = 0.f;
#pragma unroll
        for (int i = 0; i < 16; ++i) {
            h2_t hv = __builtin_bit_cast(h2_t, h2[lane + 64*i]);
            s0 = __builtin_amdgcn_fdot2(__builtin_bit_cast(h2_t, wr[0][i]), hv, s0, false);
            s1 = __builtin_amdgcn_fdot2(__builtin_bit_cast(h2_t, wr[1][i]), hv, s1, false);
            s2 = __builtin_amdgcn_fdot2(__builtin_bit_cast(h2_t, wr[2][i]), hv, s2, false);
        }
#pragma unroll
        for (int off = 32; off; off >>= 1) {
            s0 += __shfl_xor(s0, off, 64);
            s1 += __shfl_xor(s1, off, 64);
            s2 += __shfl_xor(s2, off, 64);
        }
        if (lane == 0) {
            float r  = sigmoidf_(ir + s0 + b_r);
            float uu = sigmoidf_(iz + s1 + b_z);
            float nn = tanhf(inn + r*(s2 + b_n));
            float hn = (1.f-uu)*nn + uu*hp;
            hp = hn;                                   // exact fp32 self-path
            h_gru[((size_t)(b*LSEQ + t))*DINNER + j] = hn;
            pub[w] = hn;
        }
        __syncthreads();   // pub complete + h2 WAR protection
        if (tid < 8) {
            u32 pr = pack_h2(pub[2*tid], pub[2*tid+1]);
            __hip_atomic_store(&my[(1-par)*(DINNER/2) + (j0 >> 1) + tid],
                               ((u64)(u32)(t+1) << 32) | (u64)pr,
                               __ATOMIC_RELAXED, __HIP_MEMORY_SCOPE_AGENT);
        }
    }
}

// ---------------------------------------------------------------------------
// content[bt][g] = x_conv[bt,:] . Wc[g,:]   (1024 rows x 10 gates, K=2048)
// one wave per bt row.
// ---------------------------------------------------------------------------
__global__ void __launch_bounds__(64) content_kernel(
    const float* __restrict__ xc, const float* __restrict__ Wc,
    float* __restrict__ content) {
    int bt = blockIdx.x;
    int lane = threadIdx.x;
    const float4* xr = (const float4*)(xc + (size_t)bt*DINNER);
    float4 xv[8];
#pragma unroll
    for (int r = 0; r < 8; ++r) xv[r] = xr[lane + 64*r];
#pragma unroll
    for (int g = 0; g < EVENTD; ++g) {
        const float4* wrow = (const float4*)(Wc + (size_t)g*DINNER);
        float s = 0.f;
#pragma unroll
        for (int r = 0; r < 8; ++r) {
            float4 w4 = wrow[lane + 64*r];
            s += xv[r].x*w4.x + xv[r].y*w4.y + xv[r].z*w4.z + xv[r].w*w4.w;
        }
#pragma unroll
        for (int off = 32; off; off >>= 1) s += __shfl_down(s, off, 64);
        if (lane == 0) content[(size_t)bt*EVENTD + g] = s;
    }
}

// ---------------------------------------------------------------------------
// scaling = clip(softplus(clip(h_gru . WT_w + WT_b, -10, 10)), 0.1, 10)
// ---------------------------------------------------------------------------
__global__ void scaling_kernel(const float* __restrict__ h_gru, const float* __restrict__ WT_w,
                               const float* __restrict__ WT_b, const float* __restrict__ delta,
                               float* __restrict__ scaling, float* __restrict__ stg,
                               float* __restrict__ out_last) {
    __shared__ float red[4];
    int bt = blockIdx.x;
    int tid = threadIdx.x;
    const float* h = h_gru + (size_t)bt*DINNER;
    float p = 0.f;
    for (int k = tid; k < DINNER; k += 256) p += h[k]*WT_w[k];
#pragma unroll
    for (int off = 32; off; off >>= 1) p += __shfl_down(p, off, 64);
    if ((tid & 63) == 0) red[tid >> 6] = p;
    __syncthreads();
    if (tid == 0) {
        float v = red[0]+red[1]+red[2]+red[3] + WT_b[0];
        v = fminf(fmaxf(v, -10.f), 10.f);
        float sp = log1pf(__expf(v));
        sp = fminf(fmaxf(sp, 0.1f), 10.f);
        scaling[bt] = sp;
        stg[bt] = delta[bt]*sp;
        if ((bt & (LSEQ-1)) == LSEQ-1) out_last[bt >> 9] = sp;
    }
}

__global__ void intervals_kernel(const float* __restrict__ stg, float* __restrict__ intervals) {
    int idx = blockIdx.x*256 + threadIdx.x;
    if (idx < BT) {
        float v = stg[idx];
        if (idx & (LSEQ-1)) v -= stg[idx-1];
        intervals[idx] = v;
    }
}

__global__ void bdual_kernel(const float* __restrict__ content, const float* __restrict__ stg,
                             const float* __restrict__ Wtau_w, const float* __restrict__ B0,
                             float* __restrict__ B_dual) {
    int idx = blockIdx.x*256 + threadIdx.x;
    int n = idx & 15, bt = idx >> 4;
    float v = (n < EVENTD) ? content[bt*EVENTD + n] : stg[bt]*Wtau_w[n - EVENTD];
    B_dual[idx] = B0[n]*sigmoidf_(v);
}

// ---------------------------------------------------------------------------
// Fused selective scan + y epilogue. One thread per (b,d). Dual-writes y bf16.
// ---------------------------------------------------------------------------
__global__ void scan_kernel(const float* __restrict__ base_dt, const float* __restrict__ intervals,
                            const float* __restrict__ B_dual, const float* __restrict__ x_dbl,
                            const float* __restrict__ x_conv, const float* __restrict__ xz,
                            const float* __restrict__ A_log, const float* __restrict__ D_param,
                            u16* __restrict__ y_bf) {
    int idx = blockIdx.x*256 + threadIdx.x;
    int d = idx & (DINNER-1);
    int b = idx >> 11;
    float Arow[DSTATE];
#pragma unroll
    for (int n = 0; n < DSTATE; ++n) Arow[n] = -__expf(A_log[d*DSTATE + n]);
    float Dd = D_param[d];
    float h[DSTATE];
#pragma unroll
    for (int n = 0; n < DSTATE; ++n) h[n] = 0.f;
    for (int t = 0; t < LSEQ; ++t) {
        size_t row = (size_t)b*LSEQ + t;
        float dt = intervals[row]*base_dt[row*DINNER + d];
        dt = fminf(fmaxf(dt, 1e-6f), 10.f);
        float xc = x_conv[row*DINNER + d];
        const float* Bd = B_dual + row*DSTATE;
        const float* Cc = x_dbl + row*96 + DTRANK + DSTATE;
        float y = 0.f;
#pragma unroll
        for (int n = 0; n < DSTATE; ++n) {
            float e = dt*Arow[n];
            e = fminf(fmaxf(e, -20.f), 20.f);
            float da = __expf(e);
            h[n] = da*h[n] + (dt*Bd[n])*xc;
            y += h[n]*Cc[n];
        }
        float z = xz[row*(2*DINNER) + DINNER + d];
        y_bf[row*DINNER + d] = to_bf16_((y + xc*Dd) * (z*sigmoidf_(z)));
    }
}

// ---------------------------------------------------------------------------
extern "C" void kernel_launch(void* const* d_in, const int* in_sizes, int n_in,
                              void* d_out, int out_size, void* d_ws, size_t ws_size,
                              hipStream_t stream) {
    const float* x         = (const float*)d_in[0];
    const float* delta     = (const float*)d_in[1];
    const float* in_proj_w = (const float*)d_in[2];
    const float* conv_w    = (const float*)d_in[3];
    const float* conv_b    = (const float*)d_in[4];
    const float* gru_wih   = (const float*)d_in[5];
    const float* gru_whh   = (const float*)d_in[6];
    const float* gru_bih   = (const float*)d_in[7];
    const float* gru_bhh   = (const float*)d_in[8];
    const float* WT_w      = (const float*)d_in[9];
    const float* WT_b      = (const float*)d_in[10];
    const float* Wc_w      = (const float*)d_in[11];
    const float* Wtau_w    = (const float*)d_in[12];
    const float* B0        = (const float*)d_in[13];
    const float* xproj_w   = (const float*)d_in[14];
    const float* dtproj_w  = (const float*)d_in[15];
    const float* dtproj_b  = (const float*)d_in[16];
    const float* A_log     = (const float*)d_in[17];
    const float* D_param   = (const float*)d_in[18];
    const float* outproj_w = (const float*)d_in[19];
    float* out = (float*)d_out;

    float* ws = (float*)d_ws;
    size_t off = 0;
    float* xz        = ws + off; off += (size_t)BT*2*DINNER;
    float* x_conv    = ws + off; off += (size_t)BT*DINNER;
    float* gi        = ws + off; off += (size_t)BT*3*DINNER;
    u32*   whh_h2    = (u32*)(ws + off); off += (size_t)3*DINNER*DINNER/2;  // fp16 pairs
    float* h_gru     = ws + off; off += (size_t)BT*DINNER;
    float* base_dt   = ws + off; off += (size_t)BT*DINNER;
    float* x_dbl     = ws + off; off += (size_t)BT*96;
    float* content   = ws + off; off += (size_t)BT*16;
    float* B_dual    = ws + off; off += (size_t)BT*16;
    float* scaling   = ws + off; off += BT;
    float* stg       = ws + off; off += BT;
    float* intervals = ws + off; off += BT;
    u64*   hT        = (u64*)(ws + off); off += 2*2*(DINNER/2)*2;   // 2 chains x 2 par x 1024 u64
    u16*   x_bf      = (u16*)(ws + off); off += (size_t)BT*DMODEL/2;
    u16*   inprojw_bf= (u16*)(ws + off); off += (size_t)2*DINNER*DMODEL/2;
    u16*   wih_bf    = (u16*)(ws + off); off += (size_t)3*DINNER*DINNER/2;
    u16*   outw_bf   = (u16*)(ws + off); off += (size_t)DMODEL*DINNER/2;
    u16*   xconv_bf  = (u16*)(ws + off); off += (size_t)BT*DINNER/2;
    u16*   y_bf      = (u16*)(ws + off); off += (size_t)BT*DINNER/2;

    // init tagged-h buffers (tag=0 == S_0 ready, h=0)
    hipMemsetAsync(hT, 0, (size_t)2*2*(DINNER/2)*sizeof(u64), stream);

    // weight/activation conversions
    f32_to_h2<<<4096, 256, 0, stream>>>(gru_whh, whh_h2, 3*DINNER*DINNER/2);
    f32_to_bf16<<<4096, 256, 0, stream>>>(in_proj_w, inprojw_bf, 2*DINNER*DMODEL);
    f32_to_bf16<<<4096, 256, 0, stream>>>(gru_wih, wih_bf, 3*DINNER*DINNER);
    f32_to_bf16<<<2048, 256, 0, stream>>>(outproj_w, outw_bf, DMODEL*DINNER);
    f32_to_bf16<<<2048, 256, 0, stream>>>(x, x_bf, BT*DMODEL);

    // xz = x @ in_proj_w.T            (1024 x 4096, K=1024)  [MFMA bf16]
    gemm_mfma_nt<0><<<dim3(64,16), 256, 0, stream>>>(x_bf, inprojw_bf, nullptr,
                                                     xz, BT, 2*DINNER, DMODEL);
    conv_silu<<<(BT*DINNER)/256, 256, 0, stream>>>(xz, conv_w, conv_b, x_conv, xconv_bf);

    // gi = x_conv @ gru_wih.T + bih   (1024 x 6144, K=2048)  [MFMA bf16]
    gemm_mfma_nt<1><<<dim3(96,16), 256, 0, stream>>>(xconv_bf, wih_bf, gru_bih,
                                                     gi, BT, 3*DINNER, DINNER);

    gru_kernel<<<GRU_NBLK, GRU_THREADS, 0, stream>>>(whh_h2, gi, gru_bhh, hT, h_gru);

    scaling_kernel<<<BT, 256, 0, stream>>>(h_gru, WT_w, WT_b, delta, scaling, stg,
                                           out + (size_t)BT*DMODEL);
    intervals_kernel<<<4, 256, 0, stream>>>(stg, intervals);

    // x_dbl = x_conv @ xproj_w.T      (1024 x 96, K=2048)  [fp32, precision path]
    gemm_nt<0><<<dim3(2,16), 256, 0, stream>>>(x_conv, DINNER, xproj_w, nullptr, 0.f,
                                               x_dbl, BT, 96, DINNER);
    // base_dt = softplus(dt_low @ dtproj_w.T + 2*dtproj_b)  [fp32]
    gemm_nt<1><<<dim3(32,16), 256, 0, stream>>>(x_dbl, 96, dtproj_w, dtproj_b, 2.f,
                                                base_dt, BT, DINNER, DTRANK);
    // content = x_conv @ Wc_w.T       (1024 x 10, K=2048)  [dedicated wave kernel]
    content_kernel<<<BT, 64, 0, stream>>>(x_conv, Wc_w, content);
    bdual_kernel<<<(BT*16)/256, 256, 0, stream>>>(content, stg, Wtau_w, B0, B_dual);

    scan_kernel<<<(BATCH*DINNER)/256, 256, 0, stream>>>(base_dt, intervals, B_dual, x_dbl,
                                                        x_conv, xz, A_log, D_param, y_bf);

    // out = y @ outproj_w.T           (1024 x 1024, K=2048)  [MFMA bf16]
    gemm_mfma_nt<0><<<dim3(16,16), 256, 0, stream>>>(y_bf, outw_bf, nullptr,
                                                     out, BT, DMODEL, DINNER);
}

// Round 6
// 2009.706 us; speedup vs baseline: 6.8937x; 1.3568x over previous
//
#include <hip/hip_runtime.h>
#include <hip/hip_bf16.h>

// Sizes (fixed for this problem)
#define BATCH 2
#define LSEQ 512
#define DMODEL 1024
#define DINNER 2048
#define DSTATE 16
#define DTRANK 64
#define DCONV 4
#define EVENTD 10
#define TIMED 6
#define BT (BATCH*LSEQ)   // 1024
#define NCH 32            // scan chunks
#define CL  16            // steps per chunk (NCH*CL == LSEQ)

typedef unsigned int u32;
typedef unsigned short u16;
typedef unsigned long long u64;
typedef __attribute__((ext_vector_type(8))) short short8;
typedef __attribute__((ext_vector_type(4))) float f32x4;
typedef _Float16 h2_t __attribute__((ext_vector_type(2)));

__device__ __forceinline__ float sigmoidf_(float x) { return 1.f/(1.f+__expf(-x)); }
__device__ __forceinline__ u16 to_bf16_(float f) {
    u32 u = __float_as_uint(f);
    return (u16)((u + 0x7FFFu + ((u >> 16) & 1u)) >> 16);
}
__device__ __forceinline__ u32 pack_h2(float a, float b) {
    _Float16 ha = (_Float16)a, hb = (_Float16)b;
    u16 ua, ub;
    __builtin_memcpy(&ua, &ha, 2);
    __builtin_memcpy(&ub, &hb, 2);
    return (u32)ua | ((u32)ub << 16);
}

// ---------------------------------------------------------------------------
__global__ void f32_to_bf16(const float* __restrict__ src, u16* __restrict__ dst, int n) {
    for (int i = blockIdx.x*blockDim.x + threadIdx.x; i < n; i += gridDim.x*blockDim.x)
        dst[i] = to_bf16_(src[i]);
}
__global__ void f32_to_h2(const float* __restrict__ src, u32* __restrict__ dst, int npairs) {
    for (int i = blockIdx.x*blockDim.x + threadIdx.x; i < npairs; i += gridDim.x*blockDim.x) {
        float2 v = ((const float2*)src)[i];
        dst[i] = pack_h2(v.x, v.y);
    }
}

// ---------------------------------------------------------------------------
// 128x128-tile bf16 MFMA GEMM: C[M,N] = A[M,K] @ W[N,K]^T (+bias).
// 256 thr = 4 waves; wave quadrant 64x64 = 4x4 accs of 16x16x32.
// M%128==0, N%128==0, K%32==0.
// ---------------------------------------------------------------------------
#define LSTR 40
template<int HAS_BIAS>
__global__ void __launch_bounds__(256) gemm_mfma128(
    const u16* __restrict__ A, const u16* __restrict__ W,
    const float* __restrict__ bias,
    float* __restrict__ C, int M, int N, int K) {
    __shared__ __align__(16) u16 Asl[128*LSTR];
    __shared__ __align__(16) u16 Bsl[128*LSTR];
    int tid = threadIdx.x;
    int wave = tid >> 6, lane = tid & 63;
    int m0 = blockIdx.y*128, n0 = blockIdx.x*128;
    int m0w = (wave >> 1)*64, n0w = (wave & 1)*64;
    int fr = lane & 15, quad = lane >> 4;
    f32x4 acc[4][4];
#pragma unroll
    for (int mi = 0; mi < 4; ++mi)
#pragma unroll
        for (int ni = 0; ni < 4; ++ni) acc[mi][ni] = (f32x4){0.f,0.f,0.f,0.f};

    // staging: tid<128 -> A row tid; else B row tid-128. Full 32-elem row (4x uint4)
    int srow = tid & 127;
    const u16* gp = (tid < 128) ? (A + (size_t)(m0+srow)*K) : (W + (size_t)(n0+srow)*K);
    u16* lp = (tid < 128) ? (Asl + srow*LSTR) : (Bsl + srow*LSTR);

    for (int k0 = 0; k0 < K; k0 += 32) {
        uint4 v0 = *(const uint4*)(gp + k0 + 0);
        uint4 v1 = *(const uint4*)(gp + k0 + 8);
        uint4 v2 = *(const uint4*)(gp + k0 + 16);
        uint4 v3 = *(const uint4*)(gp + k0 + 24);
        __syncthreads();
        *(uint4*)(lp + 0)  = v0;
        *(uint4*)(lp + 8)  = v1;
        *(uint4*)(lp + 16) = v2;
        *(uint4*)(lp + 24) = v3;
        __syncthreads();
        short8 af[4], bf[4];
#pragma unroll
        for (int mi = 0; mi < 4; ++mi)
            af[mi] = *(const short8*)&Asl[(m0w + mi*16 + fr)*LSTR + quad*8];
#pragma unroll
        for (int ni = 0; ni < 4; ++ni)
            bf[ni] = *(const short8*)&Bsl[(n0w + ni*16 + fr)*LSTR + quad*8];
#pragma unroll
        for (int mi = 0; mi < 4; ++mi)
#pragma unroll
            for (int ni = 0; ni < 4; ++ni)
                acc[mi][ni] = __builtin_amdgcn_mfma_f32_16x16x32_bf16(af[mi], bf[ni],
                                                                      acc[mi][ni], 0, 0, 0);
    }
#pragma unroll
    for (int ni = 0; ni < 4; ++ni) {
        int col = n0 + n0w + ni*16 + fr;
        float bb = HAS_BIAS ? bias[col] : 0.f;
#pragma unroll
        for (int mi = 0; mi < 4; ++mi) {
#pragma unroll
            for (int r = 0; r < 4; ++r) {
                int row = m0 + m0w + mi*16 + quad*4 + r;
                C[(size_t)row*N + col] = acc[mi][ni][r] + bb;
            }
        }
    }
}

// ---------------------------------------------------------------------------
// 64x64 bf16 MFMA GEMM (kept for out_proj)
// ---------------------------------------------------------------------------
template<int HAS_BIAS>
__global__ void __launch_bounds__(256) gemm_mfma_nt(
    const u16* __restrict__ A, const u16* __restrict__ W,
    const float* __restrict__ bias,
    float* __restrict__ C, int M, int N, int K) {
    __shared__ __align__(16) u16 Asl[64*LSTR];
    __shared__ __align__(16) u16 Bsl[64*LSTR];
    int tid = threadIdx.x;
    int wave = tid >> 6, lane = tid & 63;
    int m0 = blockIdx.y*64, n0 = blockIdx.x*64;
    int mstrip = wave*16;
    int fr = lane & 15, quad = lane >> 4;
    f32x4 acc[4];
#pragma unroll
    for (int nt = 0; nt < 4; ++nt) acc[nt] = (f32x4){0.f,0.f,0.f,0.f};
    int srow = tid >> 2, sk = (tid & 3)*8;
    const u16* Ap = A + (size_t)(m0+srow)*K + sk;
    const u16* Wp = W + (size_t)(n0+srow)*K + sk;
    for (int k0 = 0; k0 < K; k0 += 32) {
        uint4 av = *(const uint4*)(Ap + k0);
        uint4 bv = *(const uint4*)(Wp + k0);
        __syncthreads();
        *(uint4*)&Asl[srow*LSTR + sk] = av;
        *(uint4*)&Bsl[srow*LSTR + sk] = bv;
        __syncthreads();
        short8 af = *(const short8*)&Asl[(mstrip+fr)*LSTR + quad*8];
#pragma unroll
        for (int nt = 0; nt < 4; ++nt) {
            short8 bf = *(const short8*)&Bsl[(nt*16+fr)*LSTR + quad*8];
            acc[nt] = __builtin_amdgcn_mfma_f32_16x16x32_bf16(af, bf, acc[nt], 0, 0, 0);
        }
    }
#pragma unroll
    for (int nt = 0; nt < 4; ++nt) {
        int col = n0 + nt*16 + fr;
        float bb = HAS_BIAS ? bias[col] : 0.f;
#pragma unroll
        for (int r = 0; r < 4; ++r) {
            int row = m0 + mstrip + quad*4 + r;
            C[(size_t)row*N + col] = acc[nt][r] + bb;
        }
    }
}

// ---------------------------------------------------------------------------
// Generic fp32 GEMM (precision-sensitive projections)
// ---------------------------------------------------------------------------
template<int ACT>
__global__ void __launch_bounds__(256) gemm_nt(
    const float* __restrict__ A, int lda,
    const float* __restrict__ W,
    const float* __restrict__ bias, float bias_scale,
    float* __restrict__ C, int M, int N, int K) {
    __shared__ __align__(16) float As[16*72];
    __shared__ __align__(16) float Ws[16*72];
    int tid = threadIdx.x;
    int tx = tid & 15, ty = tid >> 4;
    int m0 = blockIdx.y*64, n0 = blockIdx.x*64;
    float acc[4][4];
#pragma unroll
    for (int i = 0; i < 4; ++i)
#pragma unroll
        for (int j = 0; j < 4; ++j) acc[i][j] = 0.f;
    int kq = tid & 15;
    int mq = tid >> 4;
    for (int k0 = 0; k0 < K; k0 += 16) {
#pragma unroll
        for (int r = 0; r < 4; ++r) {
            int m = mq + r*16;
            As[kq*72 + m] = A[(size_t)(m0+m)*lda + k0 + kq];
            int n = n0 + m;
            Ws[kq*72 + m] = (n < N) ? W[(size_t)n*K + k0 + kq] : 0.f;
        }
        __syncthreads();
#pragma unroll
        for (int kk = 0; kk < 16; ++kk) {
            float4 a4 = *(const float4*)&As[kk*72 + ty*4];
            float4 b4 = *(const float4*)&Ws[kk*72 + tx*4];
            float av[4] = {a4.x, a4.y, a4.z, a4.w};
            float bv[4] = {b4.x, b4.y, b4.z, b4.w};
#pragma unroll
            for (int i = 0; i < 4; ++i)
#pragma unroll
                for (int j = 0; j < 4; ++j) acc[i][j] += av[i]*bv[j];
        }
        __syncthreads();
    }
#pragma unroll
    for (int i = 0; i < 4; ++i) {
        int m = m0 + ty*4 + i;
#pragma unroll
        for (int j = 0; j < 4; ++j) {
            int n = n0 + tx*4 + j;
            if (n < N) {
                float v = acc[i][j];
                if (bias) v += bias_scale*bias[n];
                if (ACT == 1) v = (v > 20.f) ? v : log1pf(__expf(v));
                C[(size_t)m*N + n] = v;
            }
        }
    }
}

// ---------------------------------------------------------------------------
// Causal depthwise conv (width 4) + SiLU. Dual-writes fp32 + bf16.
// ---------------------------------------------------------------------------
__global__ void conv_silu(const float* __restrict__ xz, const float* __restrict__ conv_w,
                          const float* __restrict__ conv_b, float* __restrict__ x_conv,
                          u16* __restrict__ x_conv_bf) {
    int idx = blockIdx.x*blockDim.x + threadIdx.x;
    int d = idx & (DINNER-1);
    int bt = idx >> 11;
    int t = bt & (LSEQ-1); int b = bt >> 9;
    float acc = conv_b[d];
#pragma unroll
    for (int k = 0; k < DCONV; ++k) {
        int tt = t - (DCONV-1) + k;
        if (tt >= 0) acc += xz[((size_t)(b*LSEQ+tt))*(2*DINNER) + d] * conv_w[d*DCONV + k];
    }
    float v = acc * sigmoidf_(acc);
    x_conv[idx] = v;
    x_conv_bf[idx] = to_bf16_(v);
}

// ---------------------------------------------------------------------------
// Persistent GRU scan v5 (unchanged from R5 — verified)
// ---------------------------------------------------------------------------
#define GRU_NBLK 256
#define GRU_THREADS 1024

__global__ void __launch_bounds__(GRU_THREADS, 1) gru_kernel(
    const u32* __restrict__ whh_h2, const float* __restrict__ gi,
    const float* __restrict__ bhh, u64* __restrict__ hT,
    float* __restrict__ h_gru) {
    __shared__ u32 h2[DINNER/2];
    __shared__ float pub[16];
    int blk = blockIdx.x;
    int tid = threadIdx.x;
    int w = tid >> 6, lane = tid & 63;
    int b = blk >> 7;
    int j0 = (blk & 127) << 4;
    int j = j0 + w;

    u32 wr[3][16];
#pragma unroll
    for (int g = 0; g < 3; ++g) {
        const u32* row = whh_h2 + ((size_t)(g*DINNER + j))*(DINNER/2);
#pragma unroll
        for (int i = 0; i < 16; ++i) wr[g][i] = row[lane + 64*i];
    }
    float b_r = 0.f, b_z = 0.f, b_n = 0.f, hp = 0.f;
    if (lane == 0) { b_r = bhh[j]; b_z = bhh[DINNER+j]; b_n = bhh[2*DINNER+j]; }

    u64* my = hT + (size_t)(b*2)*(DINNER/2);
    const float* gib = gi + (size_t)b*LSEQ*(3*DINNER);

    for (int t = 0; t < LSEQ; ++t) {
        int par = t & 1;
        float ir = 0.f, iz = 0.f, inn = 0.f;
        if (lane == 0) {
            const float* g0 = gib + (size_t)t*(3*DINNER);
            ir = g0[j]; iz = g0[DINNER+j]; inn = g0[2*DINNER+j];
        }
        {
            const u64* src = my + par*(DINNER/2);
            u64 v = __hip_atomic_load(&src[tid], __ATOMIC_RELAXED,
                                      __HIP_MEMORY_SCOPE_AGENT);
            while ((u32)(v >> 32) != (u32)t) {
                __builtin_amdgcn_s_sleep(1);
                v = __hip_atomic_load(&src[tid], __ATOMIC_RELAXED,
                                      __HIP_MEMORY_SCOPE_AGENT);
            }
            h2[tid] = (u32)v;
        }
        __syncthreads();
        float s0 = 0.f, s1 = 0.f, s2 = 0.f;
#pragma unroll
        for (int i = 0; i < 16; ++i) {
            h2_t hv = __builtin_bit_cast(h2_t, h2[lane + 64*i]);
            s0 = __builtin_amdgcn_fdot2(__builtin_bit_cast(h2_t, wr[0][i]), hv, s0, false);
            s1 = __builtin_amdgcn_fdot2(__builtin_bit_cast(h2_t, wr[1][i]), hv, s1, false);
            s2 = __builtin_amdgcn_fdot2(__builtin_bit_cast(h2_t, wr[2][i]), hv, s2, false);
        }
#pragma unroll
        for (int off = 32; off; off >>= 1) {
            s0 += __shfl_xor(s0, off, 64);
            s1 += __shfl_xor(s1, off, 64);
            s2 += __shfl_xor(s2, off, 64);
        }
        if (lane == 0) {
            float r  = sigmoidf_(ir + s0 + b_r);
            float uu = sigmoidf_(iz + s1 + b_z);
            float nn = tanhf(inn + r*(s2 + b_n));
            float hn = (1.f-uu)*nn + uu*hp;
            hp = hn;
            h_gru[((size_t)(b*LSEQ + t))*DINNER + j] = hn;
            pub[w] = hn;
        }
        __syncthreads();
        if (tid < 8) {
            u32 pr = pack_h2(pub[2*tid], pub[2*tid+1]);
            __hip_atomic_store(&my[(1-par)*(DINNER/2) + (j0 >> 1) + tid],
                               ((u64)(u32)(t+1) << 32) | (u64)pr,
                               __ATOMIC_RELAXED, __HIP_MEMORY_SCOPE_AGENT);
        }
    }
}

// ---------------------------------------------------------------------------
__global__ void __launch_bounds__(64) content_kernel(
    const float* __restrict__ xc, const float* __restrict__ Wc,
    float* __restrict__ content) {
    int bt = blockIdx.x;
    int lane = threadIdx.x;
    const float4* xr = (const float4*)(xc + (size_t)bt*DINNER);
    float4 xv[8];
#pragma unroll
    for (int r = 0; r < 8; ++r) xv[r] = xr[lane + 64*r];
#pragma unroll
    for (int g = 0; g < EVENTD; ++g) {
        const float4* wrow = (const float4*)(Wc + (size_t)g*DINNER);
        float s = 0.f;
#pragma unroll
        for (int r = 0; r < 8; ++r) {
            float4 w4 = wrow[lane + 64*r];
            s += xv[r].x*w4.x + xv[r].y*w4.y + xv[r].z*w4.z + xv[r].w*w4.w;
        }
#pragma unroll
        for (int off = 32; off; off >>= 1) s += __shfl_down(s, off, 64);
        if (lane == 0) content[(size_t)bt*EVENTD + g] = s;
    }
}

__global__ void scaling_kernel(const float* __restrict__ h_gru, const float* __restrict__ WT_w,
                               const float* __restrict__ WT_b, const float* __restrict__ delta,
                               float* __restrict__ scaling, float* __restrict__ stg,
                               float* __restrict__ out_last) {
    __shared__ float red[4];
    int bt = blockIdx.x;
    int tid = threadIdx.x;
    const float* h = h_gru + (size_t)bt*DINNER;
    float p = 0.f;
    for (int k = tid; k < DINNER; k += 256) p += h[k]*WT_w[k];
#pragma unroll
    for (int off = 32; off; off >>= 1) p += __shfl_down(p, off, 64);
    if ((tid & 63) == 0) red[tid >> 6] = p;
    __syncthreads();
    if (tid == 0) {
        float v = red[0]+red[1]+red[2]+red[3] + WT_b[0];
        v = fminf(fmaxf(v, -10.f), 10.f);
        float sp = log1pf(__expf(v));
        sp = fminf(fmaxf(sp, 0.1f), 10.f);
        scaling[bt] = sp;
        stg[bt] = delta[bt]*sp;
        if ((bt & (LSEQ-1)) == LSEQ-1) out_last[bt >> 9] = sp;
    }
}

__global__ void intervals_kernel(const float* __restrict__ stg, float* __restrict__ intervals) {
    int idx = blockIdx.x*256 + threadIdx.x;
    if (idx < BT) {
        float v = stg[idx];
        if (idx & (LSEQ-1)) v -= stg[idx-1];
        intervals[idx] = v;
    }
}

__global__ void bdual_kernel(const float* __restrict__ content, const float* __restrict__ stg,
                             const float* __restrict__ Wtau_w, const float* __restrict__ B0,
                             float* __restrict__ B_dual) {
    int idx = blockIdx.x*256 + threadIdx.x;
    int n = idx & 15, bt = idx >> 4;
    float v = (n < EVENTD) ? content[bt*EVENTD + n] : stg[bt]*Wtau_w[n - EVENTD];
    B_dual[idx] = B0[n]*sigmoidf_(v);
}

// ---------------------------------------------------------------------------
// Chunked parallel selective scan.
// pass1: thread=(b,c,d). Local chunk with h0=0: emits Aprod[16], hend[16].
// pass2: thread=(b,n,d). Sequential prefix over 32 chunks: emits hinit.
// pass3: thread=(b,c,d). Re-run exact recurrence from true hinit + y epilogue.
// Layout of chunk arrays: [((b*NCH + c)*DSTATE + n)*DINNER + d]
// ---------------------------------------------------------------------------
__global__ void __launch_bounds__(256) scan_pass1(
    const float* __restrict__ base_dt, const float* __restrict__ intervals,
    const float* __restrict__ B_dual, const float* __restrict__ x_conv,
    const float* __restrict__ A_log,
    float* __restrict__ Aprod, float* __restrict__ hend) {
    int idx = blockIdx.x*256 + threadIdx.x;        // 2*32*2048
    int d = idx & (DINNER-1);
    int c = (idx >> 11) & (NCH-1);
    int b = idx >> 16;
    float Arow[DSTATE];
#pragma unroll
    for (int n = 0; n < DSTATE; ++n) Arow[n] = -__expf(A_log[d*DSTATE + n]);
    float h[DSTATE], P[DSTATE];
#pragma unroll
    for (int n = 0; n < DSTATE; ++n) { h[n] = 0.f; P[n] = 1.f; }
    for (int tt = 0; tt < CL; ++tt) {
        int t = c*CL + tt;
        size_t row = (size_t)b*LSEQ + t;
        float dt = intervals[row]*base_dt[row*DINNER + d];
        dt = fminf(fmaxf(dt, 1e-6f), 10.f);
        float xc = x_conv[row*DINNER + d];
        const float* Bd = B_dual + row*DSTATE;
#pragma unroll
        for (int n = 0; n < DSTATE; ++n) {
            float e = fminf(fmaxf(dt*Arow[n], -20.f), 20.f);
            float da = __expf(e);
            h[n] = da*h[n] + (dt*Bd[n])*xc;
            P[n] *= da;
        }
    }
    size_t base = ((size_t)(b*NCH + c)*DSTATE)*DINNER + d;
#pragma unroll
    for (int n = 0; n < DSTATE; ++n) {
        Aprod[base + (size_t)n*DINNER] = P[n];
        hend[base + (size_t)n*DINNER] = h[n];
    }
}

__global__ void __launch_bounds__(256) scan_pass2(
    const float* __restrict__ Aprod, const float* __restrict__ hend,
    float* __restrict__ hinit) {
    int idx = blockIdx.x*256 + threadIdx.x;        // 2*16*2048
    int d = idx & (DINNER-1);
    int n = (idx >> 11) & (DSTATE-1);
    int b = idx >> 15;
    float carry = 0.f;
    for (int c = 0; c < NCH; ++c) {
        size_t o = ((size_t)(b*NCH + c)*DSTATE + n)*DINNER + d;
        hinit[o] = carry;
        carry = Aprod[o]*carry + hend[o];
    }
}

__global__ void __launch_bounds__(256) scan_pass3(
    const float* __restrict__ base_dt, const float* __restrict__ intervals,
    const float* __restrict__ B_dual, const float* __restrict__ x_dbl,
    const float* __restrict__ x_conv, const float* __restrict__ xz,
    const float* __restrict__ A_log, const float* __restrict__ D_param,
    const float* __restrict__ hinit, u16* __restrict__ y_bf) {
    int idx = blockIdx.x*256 + threadIdx.x;        // 2*32*2048
    int d = idx & (DINNER-1);
    int c = (idx >> 11) & (NCH-1);
    int b = idx >> 16;
    float Arow[DSTATE];
#pragma unroll
    for (int n = 0; n < DSTATE; ++n) Arow[n] = -__expf(A_log[d*DSTATE + n]);
    float Dd = D_param[d];
    float h[DSTATE];
    size_t hib = ((size_t)(b*NCH + c)*DSTATE)*DINNER + d;
#pragma unroll
    for (int n = 0; n < DSTATE; ++n) h[n] = hinit[hib + (size_t)n*DINNER];
    for (int tt = 0; tt < CL; ++tt) {
        int t = c*CL + tt;
        size_t row = (size_t)b*LSEQ + t;
        float dt = intervals[row]*base_dt[row*DINNER + d];
        dt = fminf(fmaxf(dt, 1e-6f), 10.f);
        float xc = x_conv[row*DINNER + d];
        const float* Bd = B_dual + row*DSTATE;
        const float* Cc = x_dbl + row*96 + DTRANK + DSTATE;
        float y = 0.f;
#pragma unroll
        for (int n = 0; n < DSTATE; ++n) {
            float e = fminf(fmaxf(dt*Arow[n], -20.f), 20.f);
            float da = __expf(e);
            h[n] = da*h[n] + (dt*Bd[n])*xc;
            y += h[n]*Cc[n];
        }
        float z = xz[row*(2*DINNER) + DINNER + d];
        y_bf[row*DINNER + d] = to_bf16_((y + xc*Dd) * (z*sigmoidf_(z)));
    }
}

// ---------------------------------------------------------------------------
extern "C" void kernel_launch(void* const* d_in, const int* in_sizes, int n_in,
                              void* d_out, int out_size, void* d_ws, size_t ws_size,
                              hipStream_t stream) {
    const float* x         = (const float*)d_in[0];
    const float* delta     = (const float*)d_in[1];
    const float* in_proj_w = (const float*)d_in[2];
    const float* conv_w    = (const float*)d_in[3];
    const float* conv_b    = (const float*)d_in[4];
    const float* gru_wih   = (const float*)d_in[5];
    const float* gru_whh   = (const float*)d_in[6];
    const float* gru_bih   = (const float*)d_in[7];
    const float* gru_bhh   = (const float*)d_in[8];
    const float* WT_w      = (const float*)d_in[9];
    const float* WT_b      = (const float*)d_in[10];
    const float* Wc_w      = (const float*)d_in[11];
    const float* Wtau_w    = (const float*)d_in[12];
    const float* B0        = (const float*)d_in[13];
    const float* xproj_w   = (const float*)d_in[14];
    const float* dtproj_w  = (const float*)d_in[15];
    const float* dtproj_b  = (const float*)d_in[16];
    const float* A_log     = (const float*)d_in[17];
    const float* D_param   = (const float*)d_in[18];
    const float* outproj_w = (const float*)d_in[19];
    float* out = (float*)d_out;

    float* ws = (float*)d_ws;
    size_t off = 0;
    float* xz        = ws + off; off += (size_t)BT*2*DINNER;
    float* x_conv    = ws + off; off += (size_t)BT*DINNER;
    float* gi        = ws + off; off += (size_t)BT*3*DINNER;   // dead after GRU ->
    float* Aprod     = gi;                                      //   chunk scratch
    float* hend      = gi + (size_t)BT*DINNER;                  //   (exactly fits)
    float* hinit     = gi + (size_t)2*BT*DINNER;
    u32*   whh_h2    = (u32*)(ws + off); off += (size_t)3*DINNER*DINNER/2;
    float* h_gru     = ws + off; off += (size_t)BT*DINNER;
    float* base_dt   = ws + off; off += (size_t)BT*DINNER;
    float* x_dbl     = ws + off; off += (size_t)BT*96;
    float* content   = ws + off; off += (size_t)BT*16;
    float* B_dual    = ws + off; off += (size_t)BT*16;
    float* scaling   = ws + off; off += BT;
    float* stg       = ws + off; off += BT;
    float* intervals = ws + off; off += BT;
    u64*   hT        = (u64*)(ws + off); off += 2*2*(DINNER/2)*2;
    u16*   x_bf      = (u16*)(ws + off); off += (size_t)BT*DMODEL/2;
    u16*   inprojw_bf= (u16*)(ws + off); off += (size_t)2*DINNER*DMODEL/2;
    u16*   wih_bf    = (u16*)(ws + off); off += (size_t)3*DINNER*DINNER/2;
    u16*   outw_bf   = (u16*)(ws + off); off += (size_t)DMODEL*DINNER/2;
    u16*   xconv_bf  = (u16*)(ws + off); off += (size_t)BT*DINNER/2;
    u16*   y_bf      = (u16*)(ws + off); off += (size_t)BT*DINNER/2;

    // init tagged-h buffers (tag=0 == S_0 ready, h=0)
    hipMemsetAsync(hT, 0, (size_t)2*2*(DINNER/2)*sizeof(u64), stream);

    // weight/activation conversions
    f32_to_h2<<<4096, 256, 0, stream>>>(gru_whh, whh_h2, 3*DINNER*DINNER/2);
    f32_to_bf16<<<4096, 256, 0, stream>>>(in_proj_w, inprojw_bf, 2*DINNER*DMODEL);
    f32_to_bf16<<<4096, 256, 0, stream>>>(gru_wih, wih_bf, 3*DINNER*DINNER);
    f32_to_bf16<<<2048, 256, 0, stream>>>(outproj_w, outw_bf, DMODEL*DINNER);
    f32_to_bf16<<<2048, 256, 0, stream>>>(x, x_bf, BT*DMODEL);

    // xz = x @ in_proj_w.T            (1024 x 4096, K=1024)  [MFMA 128-tile]
    gemm_mfma128<0><<<dim3(32,8), 256, 0, stream>>>(x_bf, inprojw_bf, nullptr,
                                                    xz, BT, 2*DINNER, DMODEL);
    conv_silu<<<(BT*DINNER)/256, 256, 0, stream>>>(xz, conv_w, conv_b, x_conv, xconv_bf);

    // gi = x_conv @ gru_wih.T + bih   (1024 x 6144, K=2048)  [MFMA 128-tile]
    gemm_mfma128<1><<<dim3(48,8), 256, 0, stream>>>(xconv_bf, wih_bf, gru_bih,
                                                    gi, BT, 3*DINNER, DINNER);

    gru_kernel<<<GRU_NBLK, GRU_THREADS, 0, stream>>>(whh_h2, gi, gru_bhh, hT, h_gru);

    scaling_kernel<<<BT, 256, 0, stream>>>(h_gru, WT_w, WT_b, delta, scaling, stg,
                                           out + (size_t)BT*DMODEL);
    intervals_kernel<<<4, 256, 0, stream>>>(stg, intervals);

    // x_dbl = x_conv @ xproj_w.T      (1024 x 96, K=2048)  [fp32, precision path]
    gemm_nt<0><<<dim3(2,16), 256, 0, stream>>>(x_conv, DINNER, xproj_w, nullptr, 0.f,
                                               x_dbl, BT, 96, DINNER);
    // base_dt = softplus(dt_low @ dtproj_w.T + 2*dtproj_b)  [fp32]
    gemm_nt<1><<<dim3(32,16), 256, 0, stream>>>(x_dbl, 96, dtproj_w, dtproj_b, 2.f,
                                                base_dt, BT, DINNER, DTRANK);
    // content = x_conv @ Wc_w.T       (1024 x 10, K=2048)
    content_kernel<<<BT, 64, 0, stream>>>(x_conv, Wc_w, content);
    bdual_kernel<<<(BT*16)/256, 256, 0, stream>>>(content, stg, Wtau_w, B0, B_dual);

    // chunked parallel selective scan (+ fused y epilogue)
    scan_pass1<<<(BATCH*NCH*DINNER)/256, 256, 0, stream>>>(base_dt, intervals, B_dual,
                                                           x_conv, A_log, Aprod, hend);
    scan_pass2<<<(BATCH*DSTATE*DINNER)/256, 256, 0, stream>>>(Aprod, hend, hinit);
    scan_pass3<<<(BATCH*NCH*DINNER)/256, 256, 0, stream>>>(base_dt, intervals, B_dual,
                                                           x_dbl, x_conv, xz, A_log,
                                                           D_param, hinit, y_bf);

    // out = y @ outproj_w.T           (1024 x 1024, K=2048)  [MFMA 64-tile]
    gemm_mfma_nt<0><<<dim3(16,16), 256, 0, stream>>>(y_bf, outw_bf, nullptr,
                                                     out, BT, DMODEL, DINNER);
}